// Round 12
// baseline (571.141 us; speedup 1.0000x reference)
//
#include <hip/hip_runtime.h>
#include <hip/hip_bf16.h>
#include <cstddef>
#include <cstdint>

#define TPB 256
#define HID 128
#define GATD 512
#define HEADS 4

typedef __attribute__((ext_vector_type(8))) short bf16x8;
typedef __attribute__((ext_vector_type(4))) float f32x4;

__device__ __forceinline__ float lrelu02(float x) { return x > 0.0f ? x : 0.2f * x; }

__device__ __forceinline__ unsigned short f2bf_rn(float f) {
  uint32_t u = __float_as_uint(f);
  u += 0x7fff + ((u >> 16) & 1);
  return (unsigned short)(u >> 16);
}
__device__ __forceinline__ float bf2f(unsigned short h) {
  return __uint_as_float(((uint32_t)h) << 16);
}
__device__ __forceinline__ float bflo(uint32_t u) { return __uint_as_float(u << 16); }
__device__ __forceinline__ float bfhi(uint32_t u) { return __uint_as_float(u & 0xffff0000u); }

// ---------------- utility ----------------
__global__ void k_zero(int* __restrict__ p, int n) {
  int i = blockIdx.x * blockDim.x + threadIdx.x;
  if (i < n) p[i] = 0;
}

// ---------------- CSR build ----------------
__global__ void k_hist(const int* __restrict__ dst, int* __restrict__ cnt, int E) {
  int i = blockIdx.x * blockDim.x + threadIdx.x;
  if (i < E) atomicAdd(&cnt[dst[i]], 1);
}

__global__ __launch_bounds__(256) void k_scan_blk(const int* __restrict__ cnt,
                                                  int* __restrict__ rowp,
                                                  int* __restrict__ bsum,
                                                  float* __restrict__ dinv, int n) {
  __shared__ int wsum[4];
  const int tid = threadIdx.x, lane = tid & 63, wid = tid >> 6;
  const int base = blockIdx.x * 1024 + tid * 4;
  int v[4];
#pragma unroll
  for (int q = 0; q < 4; ++q) {
    int idx = base + q;
    v[q] = (idx < n) ? cnt[idx] : 0;
    if (idx < n) dinv[idx] = rsqrtf((float)(v[q] + 1));  // +1 self loop
  }
  int s = v[0] + v[1] + v[2] + v[3];
  int sc = s;
#pragma unroll
  for (int off = 1; off < 64; off <<= 1) {
    int t = __shfl_up(sc, off);
    if (lane >= off) sc += t;
  }
  if (lane == 63) wsum[wid] = sc;
  __syncthreads();
  int woff = 0;
#pragma unroll
  for (int w = 0; w < 4; ++w)
    if (w < wid) woff += wsum[w];
  int run = woff + sc - s;
#pragma unroll
  for (int q = 0; q < 4; ++q) {
    int idx = base + q;
    if (idx < n) rowp[idx] = run;
    run += v[q];
  }
  if (tid == 255) bsum[blockIdx.x] = woff + sc;
}

__global__ __launch_bounds__(256) void k_scan_top(int* __restrict__ bsum, int nb) {
  __shared__ int sm[256];
  const int tid = threadIdx.x;
  int v = (tid < nb) ? bsum[tid] : 0;
  sm[tid] = v;
  __syncthreads();
  for (int off = 1; off < 256; off <<= 1) {
    int t = (tid >= off) ? sm[tid - off] : 0;
    __syncthreads();
    sm[tid] += t;
    __syncthreads();
  }
  int incl = sm[tid];
  if (tid < nb) bsum[tid] = incl - v;
  if (tid == nb - 1) bsum[nb] = incl;
}

__global__ void k_scan_add(int* __restrict__ rowp, const int* __restrict__ bsum,
                           int n, int nb) {
  int i = blockIdx.x * blockDim.x + threadIdx.x;
  if (i < n) rowp[i] += bsum[i >> 10];
  if (i == 0) rowp[n] = bsum[nb];
}

__global__ void k_fill(const int* __restrict__ src, const int* __restrict__ dst,
                       const int* __restrict__ rowp, int* __restrict__ cur,
                       int* __restrict__ colsrc, int E) {
  int i = blockIdx.x * blockDim.x + threadIdx.x;
  if (i < E) {
    int d = dst[i];
    int pos = rowp[d] + atomicAdd(&cur[d], 1);
    colsrc[pos] = src[i];
  }
}

// ---------------- weight split (transposed hi/lo planes): Win, Wg1, Wg2 ----------------
__global__ void k_splitw_all(const float* __restrict__ Win, const float* __restrict__ Wg1,
                             const float* __restrict__ Wg2,
                             unsigned short* __restrict__ WinTh, unsigned short* __restrict__ WinTl,
                             unsigned short* __restrict__ Wg1Th, unsigned short* __restrict__ Wg1Tl,
                             unsigned short* __restrict__ Wg2Th, unsigned short* __restrict__ Wg2Tl) {
  int t = blockIdx.x * blockDim.x + threadIdx.x;
  const float* W;
  unsigned short *H, *L;
  int K, NC, r;
  if (t < 32768)      { W = Win; H = WinTh; L = WinTl; K = 256; NC = 128; r = t; }
  else if (t < 49152) { W = Wg1; H = Wg1Th; L = Wg1Tl; K = 128; NC = 128; r = t - 32768; }
  else if (t < 65536) { W = Wg2; H = Wg2Th; L = Wg2Tl; K = 128; NC = 128; r = t - 49152; }
  else return;
  int k = r / NC, n2 = r % NC;
  float v = W[r];
  unsigned short h = f2bf_rn(v);
  H[(size_t)n2 * K + k] = h;
  L[(size_t)n2 * K + k] = f2bf_rn(v - bf2f(h));
}

// ---------------- merged prep: waT logits-fold, V-fold planes, cbias, WoutT transpose ----------------
__global__ __launch_bounds__(256) void k_prep(const float* __restrict__ Wgat,
                                              const float* __restrict__ att_src,
                                              const float* __restrict__ att_dst,
                                              const float* __restrict__ Wao,
                                              const float* __restrict__ bgat,
                                              const float* __restrict__ bao,
                                              const float* __restrict__ Wout,
                                              float* __restrict__ waT,
                                              unsigned short* __restrict__ VTh,
                                              unsigned short* __restrict__ VTl,
                                              float* __restrict__ cb,
                                              float* __restrict__ WoutT) {
  int t = blockIdx.x * blockDim.x + threadIdx.x;
  if (t < 1024) {
    // waT[p][k]: p<4 src head p; p>=4 dst head p-4
    int p = t >> 7, k = t & 127;
    int h = p & 3;
    const float* av = (p < 4 ? att_src : att_dst) + h * HID;
    const float* wrow = Wgat + (size_t)k * GATD + h * HID;
    float s = 0.f;
#pragma unroll 4
    for (int c = 0; c < HID; ++c) s = fmaf(wrow[c], av[c], s);
    waT[t] = s;
  } else if (t < 1024 + 65536) {
    // VT[j][k], j = c*4+h head-interleaved: V = Wgat_h @ Wao_h folded
    int r = t - 1024;
    int j = r >> 7, k = r & 127;
    int c = j >> 2, h = j & 3;
    const float* wg = Wgat + (size_t)k * GATD + h * HID;
    const float* wa = Wao + (size_t)(h * HID) * HID + c;
    float s = 0.f;
#pragma unroll 4
    for (int d = 0; d < HID; ++d) s = fmaf(wg[d], wa[(size_t)d * HID], s);
    unsigned short hi = f2bf_rn(s);
    VTh[(size_t)j * HID + k] = hi;
    VTl[(size_t)j * HID + k] = f2bf_rn(s - bf2f(hi));
  } else if (t < 1024 + 65536 + 128) {
    // cb[c] = bao[c] + sum_d bgat[d]*Wao[d][c]
    int c = t - 1024 - 65536;
    float s = bao[c];
    for (int d = 0; d < GATD; ++d) s = fmaf(bgat[d], Wao[(size_t)d * HID + c], s);
    cb[c] = s;
  } else if (t < 1024 + 65536 + 128 + 8192) {
    // WoutT[c'][c] = Wout[c][c']
    int r = t - 1024 - 65536 - 128;
    int cp = r >> 7, c = r & 127;
    WoutT[(size_t)cp * HID + c] = Wout[(size_t)c * 64 + cp];
  }
}

// ---------------- weight-stationary MFMA GEMM ----------------
// C = act(A @ W + bias); W as (BhT,BlT)[NC,KTOT] transposed hi/lo planes in LDS per chunk.
// AMODE 0: A = (Ah,Al) pre-split planes.  AMODE 1: Ah = fp32 A, split in registers.
// A*B ~= Ah*Bh + Ah*Bl + Al*Bh.  OUTM: 0=f32, 1=bf16, 2=hi/lo planes.
template <int KTOT, int KC, int NCB, bool RELU, bool BIAS, int OUTM, int AMODE>
__global__ __launch_bounds__(256) void k_gemm5(
    const unsigned short* __restrict__ Ah, const unsigned short* __restrict__ Al,
    const unsigned short* __restrict__ BhT, const unsigned short* __restrict__ BlT,
    const float* __restrict__ bias, void* __restrict__ Cv, void* __restrict__ Cv2,
    int M, int NC) {
  constexpr int NSUB = KC / 32;
  constexpr int NCHUNK = KTOT / KC;
  constexpr int NCF = NCB / 16;
  constexpr int UNITS = NSUB * 2 * 4 * NCB;
  __shared__ alignas(16) unsigned short Bs[NSUB][2][4][NCB][8];
  const int tid = threadIdx.x, lane = tid & 63, wid = tid >> 6;
  const int m0 = blockIdx.x * 64;
  const int n0 = blockIdx.y * NCB;
  const int fr = lane & 15, g = lane >> 4;
  const int arow = m0 + wid * 16 + fr;
  const bool aok = arow < M;
  const size_t abase = (size_t)arow * KTOT;

  f32x4 acc[NCF];
#pragma unroll
  for (int cf = 0; cf < NCF; ++cf) acc[cf] = (f32x4){0.f, 0.f, 0.f, 0.f};

  for (int c = 0; c < NCHUNK; ++c) {
    const int c0 = c * KC;
    if (c > 0) __syncthreads();
#pragma unroll
    for (int it = 0; it < UNITS / 256; ++it) {
      const int u = tid + it * 256;
      const int n = u % NCB;
      int rest = u / NCB;
      const int kg = rest & 3;
      rest >>= 2;
      const int p = rest & 1;
      const int sub = rest >> 1;
      const unsigned short* sp =
          (p ? BlT : BhT) + (size_t)(n0 + n) * KTOT + c0 + sub * 32 + kg * 8;
      *(uint4*)&Bs[sub][p][kg][n][0] = *(const uint4*)sp;
    }
    __syncthreads();
#pragma unroll
    for (int sub = 0; sub < NSUB; ++sub) {
      const int kb = c0 + sub * 32 + g * 8;
      bf16x8 a_h = {}, a_l = {};
      if (aok) {
        if (AMODE == 0) {
          a_h = *(const bf16x8*)(Ah + abase + kb);
          a_l = *(const bf16x8*)(Al + abase + kb);
        } else {
          const float* Af = (const float*)Ah + abase + kb;
          float4 q0 = *(const float4*)Af;
          float4 q1 = *(const float4*)(Af + 4);
          float av[8] = {q0.x, q0.y, q0.z, q0.w, q1.x, q1.y, q1.z, q1.w};
          union { bf16x8 v; uint32_t u4[4]; } Hu, Lu;
#pragma unroll
          for (int q = 0; q < 4; ++q) {
            unsigned short h0 = f2bf_rn(av[2 * q]);
            unsigned short h1 = f2bf_rn(av[2 * q + 1]);
            unsigned short l0 = f2bf_rn(av[2 * q] - bf2f(h0));
            unsigned short l1 = f2bf_rn(av[2 * q + 1] - bf2f(h1));
            Hu.u4[q] = (uint32_t)h0 | ((uint32_t)h1 << 16);
            Lu.u4[q] = (uint32_t)l0 | ((uint32_t)l1 << 16);
          }
          a_h = Hu.v;
          a_l = Lu.v;
        }
      }
#pragma unroll
      for (int cf = 0; cf < NCF; ++cf) {
        bf16x8 b_h = *(const bf16x8*)&Bs[sub][0][g][cf * 16 + fr][0];
        bf16x8 b_l = *(const bf16x8*)&Bs[sub][1][g][cf * 16 + fr][0];
        acc[cf] = __builtin_amdgcn_mfma_f32_16x16x32_bf16(a_h, b_h, acc[cf], 0, 0, 0);
        acc[cf] = __builtin_amdgcn_mfma_f32_16x16x32_bf16(a_h, b_l, acc[cf], 0, 0, 0);
        acc[cf] = __builtin_amdgcn_mfma_f32_16x16x32_bf16(a_l, b_h, acc[cf], 0, 0, 0);
      }
    }
  }
#pragma unroll
  for (int cf = 0; cf < NCF; ++cf) {
    const int col = n0 + cf * 16 + fr;
    const float bv = BIAS ? bias[col] : 0.f;
#pragma unroll
    for (int r = 0; r < 4; ++r) {
      const int grow = m0 + wid * 16 + g * 4 + r;
      if (grow < M) {
        float v = acc[cf][r] + bv;
        if (RELU) v = fmaxf(v, 0.f);
        const size_t idx = (size_t)grow * NC + col;
        if (OUTM == 0) {
          ((float*)Cv)[idx] = v;
        } else if (OUTM == 1) {
          ((unsigned short*)Cv)[idx] = f2bf_rn(v);
        } else {
          unsigned short h = f2bf_rn(v);
          ((unsigned short*)Cv)[idx] = h;
          ((unsigned short*)Cv2)[idx] = f2bf_rn(v - bf2f(h));
        }
      }
    }
  }
}

// ---------------- GCN aggregate (bf16 gather) + bias + LN + ReLU (+residual, +GAT logits) ----------------
template <bool L2>
__global__ __launch_bounds__(256) void k_gcn_agg(
    const unsigned short* __restrict__ xwb, const float* __restrict__ dinv,
    const int* __restrict__ rowp, const int* __restrict__ colsrc,
    const float* __restrict__ bias, const float* __restrict__ gamma,
    const float* __restrict__ beta,
    const unsigned short* __restrict__ resh, const unsigned short* __restrict__ resl,
    unsigned short* __restrict__ oh, unsigned short* __restrict__ ol,
    const float* __restrict__ waT, float* __restrict__ a_s, float* __restrict__ a_d,
    int n) {
  __shared__ float w[8][HID];
  if (L2) {
    for (int t = threadIdx.x; t < 8 * HID; t += 256) ((float*)w)[t] = waT[t];
    __syncthreads();
  }
  const int lane = threadIdx.x & 63;
  const int i = blockIdx.x * 4 + (threadIdx.x >> 6);
  if (i >= n) return;
  const float di = dinv[i];
  const int c = lane * 2;
  uint32_t v0 = *(const uint32_t*)(xwb + (size_t)i * HID + c);
  float a0 = bflo(v0) * di * di, a1 = bfhi(v0) * di * di;  // self loop
  float b0 = 0.f, b1 = 0.f;
  const int e0 = rowp[i], e1 = rowp[i + 1];
  int j = e0;
  for (; j + 7 < e1; j += 8) {
    int ss[8];
    float ww[8];
    uint32_t uu[8];
#pragma unroll
    for (int q = 0; q < 8; ++q) ss[q] = colsrc[j + q];
#pragma unroll
    for (int q = 0; q < 8; ++q) ww[q] = dinv[ss[q]] * di;
#pragma unroll
    for (int q = 0; q < 8; ++q) uu[q] = *(const uint32_t*)(xwb + (size_t)ss[q] * HID + c);
#pragma unroll
    for (int q = 0; q < 8; ++q) {
      if (q & 1) {
        b0 = fmaf(bflo(uu[q]), ww[q], b0);
        b1 = fmaf(bfhi(uu[q]), ww[q], b1);
      } else {
        a0 = fmaf(bflo(uu[q]), ww[q], a0);
        a1 = fmaf(bfhi(uu[q]), ww[q], a1);
      }
    }
  }
  for (; j < e1; ++j) {
    int s0 = colsrc[j];
    float w0 = dinv[s0] * di;
    uint32_t u0 = *(const uint32_t*)(xwb + (size_t)s0 * HID + c);
    a0 = fmaf(bflo(u0), w0, a0);
    a1 = fmaf(bfhi(u0), w0, a1);
  }
  a0 += b0;
  a1 += b1;
  a0 += bias[c];
  a1 += bias[c + 1];
  float s1 = a0 + a1, s2 = a0 * a0 + a1 * a1;
#pragma unroll
  for (int m = 32; m >= 1; m >>= 1) {
    s1 += __shfl_xor(s1, m);
    s2 += __shfl_xor(s2, m);
  }
  float mu = s1 * (1.0f / HID);
  float var = s2 * (1.0f / HID) - mu * mu;
  float rstd = rsqrtf(var + 1e-5f);
  float y0 = fmaxf((a0 - mu) * rstd * gamma[c] + beta[c], 0.0f);
  float y1 = fmaxf((a1 - mu) * rstd * gamma[c + 1] + beta[c + 1], 0.0f);
  if (L2) {
    uint32_t rh = *(const uint32_t*)(resh + (size_t)i * HID + c);
    uint32_t rl = *(const uint32_t*)(resl + (size_t)i * HID + c);
    y0 += bflo(rh) + bflo(rl);
    y1 += bfhi(rh) + bfhi(rl);
  }
  unsigned short ph0 = f2bf_rn(y0), ph1 = f2bf_rn(y1);
  uint32_t hw = (uint32_t)ph0 | ((uint32_t)ph1 << 16);
  uint32_t lw = (uint32_t)f2bf_rn(y0 - bf2f(ph0)) |
                ((uint32_t)f2bf_rn(y1 - bf2f(ph1)) << 16);
  *(uint32_t*)(oh + (size_t)i * HID + c) = hw;
  *(uint32_t*)(ol + (size_t)i * HID + c) = lw;
  if (L2) {
    float p[8];
#pragma unroll
    for (int h = 0; h < 8; ++h) p[h] = y0 * w[h][c] + y1 * w[h][c + 1];
#pragma unroll
    for (int m = 32; m >= 1; m >>= 1) {
#pragma unroll
      for (int h = 0; h < 8; ++h) p[h] += __shfl_xor(p[h], m);
    }
    if (lane == 0) {
      a_s[i * 4 + 0] = p[0]; a_s[i * 4 + 1] = p[1];
      a_s[i * 4 + 2] = p[2]; a_s[i * 4 + 3] = p[3];
      a_d[i * 4 + 0] = p[4]; a_d[i * 4 + 1] = p[5];
      a_d[i * 4 + 2] = p[6]; a_d[i * 4 + 3] = p[7];
    }
  }
}

// ---------------- GAT softmax-aggregate on folded z + fused Wout epilogue -> d_out ----------------
// z row layout: elem c*4+h (head-interleaved). att = relu(sum_h agg_h + cb);
// out[i][c'] = bout[c'] + sum_c att[c] * WoutT[c'][c].
__global__ __launch_bounds__(256) void k_gat_agg3(const unsigned short* __restrict__ zb,
                                                  const float* __restrict__ a_s,
                                                  const float* __restrict__ a_d,
                                                  const int* __restrict__ rowp,
                                                  const int* __restrict__ colsrc,
                                                  const float* __restrict__ cb,
                                                  const float* __restrict__ WoutT,
                                                  const float* __restrict__ bout,
                                                  float* __restrict__ outp,
                                                  int n) {
  __shared__ float4 albuf[4][64];
  __shared__ int sbuf[4][64];
  __shared__ float attbuf[4][HID];
  const int lane = threadIdx.x & 63;
  const int wid = threadIdx.x >> 6;
  const int i = blockIdx.x * 4 + wid;
  if (i >= n) return;
  const float4 adv = *(const float4*)(a_d + i * 4);
  const float4 asv = *(const float4*)(a_s + i * 4);
  float es0 = lrelu02(asv.x + adv.x);
  float es1 = lrelu02(asv.y + adv.y);
  float es2 = lrelu02(asv.z + adv.z);
  float es3 = lrelu02(asv.w + adv.w);
  const int e0 = rowp[i], e1 = rowp[i + 1];
  // pass 1: max
  float m0 = es0, m1 = es1, m2 = es2, m3 = es3;
  for (int j = e0 + lane; j < e1; j += 64) {
    int s = colsrc[j];
    const float4 av = *(const float4*)(a_s + s * 4);
    m0 = fmaxf(m0, lrelu02(av.x + adv.x));
    m1 = fmaxf(m1, lrelu02(av.y + adv.y));
    m2 = fmaxf(m2, lrelu02(av.z + adv.z));
    m3 = fmaxf(m3, lrelu02(av.w + adv.w));
  }
#pragma unroll
  for (int m = 32; m >= 1; m >>= 1) {
    m0 = fmaxf(m0, __shfl_xor(m0, m));
    m1 = fmaxf(m1, __shfl_xor(m1, m));
    m2 = fmaxf(m2, __shfl_xor(m2, m));
    m3 = fmaxf(m3, __shfl_xor(m3, m));
  }
  // pass 2: denom
  float d0 = 0.f, d1 = 0.f, d2 = 0.f, d3 = 0.f;
  for (int j = e0 + lane; j < e1; j += 64) {
    int s = colsrc[j];
    const float4 av = *(const float4*)(a_s + s * 4);
    d0 += __expf(lrelu02(av.x + adv.x) - m0);
    d1 += __expf(lrelu02(av.y + adv.y) - m1);
    d2 += __expf(lrelu02(av.z + adv.z) - m2);
    d3 += __expf(lrelu02(av.w + adv.w) - m3);
  }
#pragma unroll
  for (int m = 32; m >= 1; m >>= 1) {
    d0 += __shfl_xor(d0, m);
    d1 += __shfl_xor(d1, m);
    d2 += __shfl_xor(d2, m);
    d3 += __shfl_xor(d3, m);
  }
  d0 += __expf(es0 - m0);
  d1 += __expf(es1 - m1);
  d2 += __expf(es2 - m2);
  d3 += __expf(es3 - m3);
  const float inv0 = 1.0f / d0, inv1 = 1.0f / d1, inv2 = 1.0f / d2, inv3 = 1.0f / d3;
  const float4 asf = make_float4(__expf(es0 - m0) * inv0, __expf(es1 - m1) * inv1,
                                 __expf(es2 - m2) * inv2, __expf(es3 - m3) * inv3);
  const int col8 = lane * 8;  // elems [lane*8, lane*8+8): c0=lane*2 (h0..3), c0+1 (h0..3)
  uint4 u = *(const uint4*)(zb + (size_t)i * GATD + col8);
  float4 accC0 = make_float4(bflo(u.x) * asf.x, bfhi(u.x) * asf.y,
                             bflo(u.y) * asf.z, bfhi(u.y) * asf.w);
  float4 accC1 = make_float4(bflo(u.z) * asf.x, bfhi(u.z) * asf.y,
                             bflo(u.w) * asf.z, bfhi(u.w) * asf.w);
  // pass 3: chunked -- 64 lanes compute 64 edge-alphas, then all lanes stream messages
  for (int b = e0; b < e1; b += 64) {
    int j = b + lane;
    if (j < e1) {
      int s = colsrc[j];
      const float4 av = *(const float4*)(a_s + s * 4);
      albuf[wid][lane] = make_float4(__expf(lrelu02(av.x + adv.x) - m0) * inv0,
                                     __expf(lrelu02(av.y + adv.y) - m1) * inv1,
                                     __expf(lrelu02(av.z + adv.z) - m2) * inv2,
                                     __expf(lrelu02(av.w + adv.w) - m3) * inv3);
      sbuf[wid][lane] = s;
    }
    asm volatile("s_waitcnt lgkmcnt(0)" ::: "memory");
    const int cnt = min(64, e1 - b);
    for (int t = 0; t < cnt; ++t) {
      float4 a4 = albuf[wid][t];
      int s = sbuf[wid][t];
      uint4 w = *(const uint4*)(zb + (size_t)s * GATD + col8);
      accC0.x = fmaf(bflo(w.x), a4.x, accC0.x);
      accC0.y = fmaf(bfhi(w.x), a4.y, accC0.y);
      accC0.z = fmaf(bflo(w.y), a4.z, accC0.z);
      accC0.w = fmaf(bfhi(w.y), a4.w, accC0.w);
      accC1.x = fmaf(bflo(w.z), a4.x, accC1.x);
      accC1.y = fmaf(bfhi(w.z), a4.y, accC1.y);
      accC1.z = fmaf(bflo(w.w), a4.z, accC1.z);
      accC1.w = fmaf(bfhi(w.w), a4.w, accC1.w);
    }
  }
  const int c0 = lane * 2;
  float2 cbv = *(const float2*)(cb + c0);
  float o0 = fmaxf(accC0.x + accC0.y + accC0.z + accC0.w + cbv.x, 0.0f);
  float o1 = fmaxf(accC1.x + accC1.y + accC1.z + accC1.w + cbv.y, 0.0f);
  // fused Wout epilogue: share att row via wave-local LDS, each lane owns out col `lane`
  attbuf[wid][c0] = o0;
  attbuf[wid][c0 + 1] = o1;
  asm volatile("s_waitcnt lgkmcnt(0)" ::: "memory");
  float acc = bout[lane];
  const float* wrow = WoutT + (size_t)lane * HID;
#pragma unroll 8
  for (int c = 0; c < HID; c += 4) {
    float4 wv = *(const float4*)(wrow + c);
    acc = fmaf(attbuf[wid][c], wv.x, acc);
    acc = fmaf(attbuf[wid][c + 1], wv.y, acc);
    acc = fmaf(attbuf[wid][c + 2], wv.z, acc);
    acc = fmaf(attbuf[wid][c + 3], wv.w, acc);
  }
  outp[(size_t)i * 64 + lane] = acc;
}

extern "C" void kernel_launch(void* const* d_in, const int* in_sizes, int n_in,
                              void* d_out, int out_size, void* d_ws, size_t ws_size,
                              hipStream_t stream) {
  const float* x = (const float*)d_in[0];
  const int* ei = (const int*)d_in[1];
  const float* Win = (const float*)d_in[2];
  const float* bin = (const float*)d_in[3];
  const float* Wg1 = (const float*)d_in[4];
  const float* bg1 = (const float*)d_in[5];
  const float* g1g = (const float*)d_in[6];
  const float* g1b = (const float*)d_in[7];
  const float* Wg2 = (const float*)d_in[8];
  const float* bg2 = (const float*)d_in[9];
  const float* g2g = (const float*)d_in[10];
  const float* g2b = (const float*)d_in[11];
  const float* Wgat = (const float*)d_in[12];
  const float* att_s = (const float*)d_in[13];
  const float* att_d = (const float*)d_in[14];
  const float* bgat = (const float*)d_in[15];
  const float* Wao = (const float*)d_in[16];
  const float* bao = (const float*)d_in[17];
  const float* Wout = (const float*)d_in[18];
  const float* bout = (const float*)d_in[19];

  const int N = in_sizes[0] / 256;
  const int E = in_sizes[1] / 2;
  const int* src = ei;
  const int* dst = ei + E;

  // ---- workspace layout (bytes), ~145 MB ----
  char* base = (char*)d_ws;
  size_t off = 0;
  unsigned short* h0h = (unsigned short*)(base + off); off += (size_t)N * HID * 2;
  unsigned short* h0l = (unsigned short*)(base + off); off += (size_t)N * HID * 2;
  unsigned short* x1h = (unsigned short*)(base + off); off += (size_t)N * HID * 2;
  unsigned short* x1l = (unsigned short*)(base + off); off += (size_t)N * HID * 2;
  unsigned short* xwb = (unsigned short*)(base + off); off += (size_t)N * HID * 2;
  unsigned short* x2h = (unsigned short*)(base + off); off += (size_t)N * HID * 2;
  unsigned short* x2l = (unsigned short*)(base + off); off += (size_t)N * HID * 2;
  unsigned short* zb = (unsigned short*)(base + off); off += (size_t)N * GATD * 2;
  float* dinv = (float*)(base + off);                 off += (size_t)N * 4;
  float* a_s = (float*)(base + off);                  off += (size_t)N * 16;
  float* a_d = (float*)(base + off);                  off += (size_t)N * 16;
  float* waT = (float*)(base + off);                  off += 4096;
  float* cb = (float*)(base + off);                   off += 512;
  float* WoutT = (float*)(base + off);                off += 64 * 128 * 4;
  unsigned short *WinTh, *WinTl, *Wg1Th, *Wg1Tl, *Wg2Th, *Wg2Tl, *VTh, *VTl;
  WinTh = (unsigned short*)(base + off); off += 256 * 128 * 2;
  WinTl = (unsigned short*)(base + off); off += 256 * 128 * 2;
  Wg1Th = (unsigned short*)(base + off); off += 128 * 128 * 2;
  Wg1Tl = (unsigned short*)(base + off); off += 128 * 128 * 2;
  Wg2Th = (unsigned short*)(base + off); off += 128 * 128 * 2;
  Wg2Tl = (unsigned short*)(base + off); off += 128 * 128 * 2;
  VTh = (unsigned short*)(base + off);   off += 512 * 128 * 2;
  VTl = (unsigned short*)(base + off);   off += 512 * 128 * 2;
  int* rowp = (int*)(base + off);   off += (size_t)(N + 1) * 4;
  int* colsrc = (int*)(base + off); off += (size_t)E * 4;
  const int nb2 = (N + 1023) / 1024;
  int* bsum = (int*)(base + off);   off += (size_t)(nb2 + 2) * 4;
  int* cnt = (int*)zb;  // alias: dead before zb is written
  int* cur = cnt + N;

  const int eb = (E + TPB - 1) / TPB;
  const int zbk = (2 * N + TPB - 1) / TPB;
  const int ab = (N + 3) / 4;
  const int gm = (N + 63) / 64;

  // CSR + prep
  k_zero<<<zbk, TPB, 0, stream>>>(cnt, 2 * N);
  k_hist<<<eb, TPB, 0, stream>>>(dst, cnt, E);
  k_scan_blk<<<nb2, 256, 0, stream>>>(cnt, rowp, bsum, dinv, N);
  k_scan_top<<<1, 256, 0, stream>>>(bsum, nb2);
  k_scan_add<<<(N + 255) / 256, 256, 0, stream>>>(rowp, bsum, N, nb2);
  k_fill<<<eb, TPB, 0, stream>>>(src, dst, rowp, cur, colsrc, E);
  k_prep<<<(1024 + 65536 + 128 + 8192 + 255) / 256, 256, 0, stream>>>(
      Wgat, att_s, att_d, Wao, bgat, bao, Wout, waT, VTh, VTl, cb, WoutT);
  k_splitw_all<<<(65536 + 255) / 256, 256, 0, stream>>>(
      Win, Wg1, Wg2, WinTh, WinTl, Wg1Th, Wg1Tl, Wg2Th, Wg2Tl);

  // h0 = relu(x @ Win + bin) -> planes    [fp32 A split in regs]
  k_gemm5<256, 64, 128, true, true, 2, 1><<<dim3(gm, 1), 256, 0, stream>>>(
      (const unsigned short*)x, nullptr, WinTh, WinTl, bin, h0h, h0l, N, 128);
  // GCN layer 1: xwb = bf16(h0 @ Wg1)
  k_gemm5<128, 64, 128, false, false, 1, 0><<<dim3(gm, 1), 256, 0, stream>>>(
      h0h, h0l, Wg1Th, Wg1Tl, nullptr, xwb, nullptr, N, 128);
  k_gcn_agg<false><<<ab, 256, 0, stream>>>(xwb, dinv, rowp, colsrc, bg1, g1g, g1b,
                                           nullptr, nullptr, x1h, x1l,
                                           nullptr, nullptr, nullptr, N);
  // GCN layer 2 (+residual, +fused GAT logits)
  k_gemm5<128, 64, 128, false, false, 1, 0><<<dim3(gm, 1), 256, 0, stream>>>(
      x1h, x1l, Wg2Th, Wg2Tl, nullptr, xwb, nullptr, N, 128);
  k_gcn_agg<true><<<ab, 256, 0, stream>>>(xwb, dinv, rowp, colsrc, bg2, g2g, g2b,
                                          x1h, x1l, x2h, x2l, waT, a_s, a_d, N);
  // z = bf16(x2 @ V)  [head-interleaved cols; NCB=256, KC=32, y=2]
  k_gemm5<128, 32, 256, false, false, 1, 0><<<dim3(gm, 2), 256, 0, stream>>>(
      x2h, x2l, VTh, VTl, nullptr, zb, nullptr, N, 512);
  // softmax-aggregate on z + fused Wout epilogue -> d_out directly
  k_gat_agg3<<<ab, 256, 0, stream>>>(zb, a_s, a_d, rowp, colsrc, cb, WoutT, bout,
                                     (float*)d_out, N);
}

// Round 13
// 488.708 us; speedup vs baseline: 1.1687x; 1.1687x over previous
//
#include <hip/hip_runtime.h>
#include <hip/hip_bf16.h>
#include <cstddef>
#include <cstdint>

#define TPB 256
#define HID 128
#define GATD 512
#define HEADS 4

typedef __attribute__((ext_vector_type(8))) short bf16x8;
typedef __attribute__((ext_vector_type(4))) float f32x4;

__device__ __forceinline__ float lrelu02(float x) { return x > 0.0f ? x : 0.2f * x; }

__device__ __forceinline__ unsigned short f2bf_rn(float f) {
  uint32_t u = __float_as_uint(f);
  u += 0x7fff + ((u >> 16) & 1);
  return (unsigned short)(u >> 16);
}
__device__ __forceinline__ float bf2f(unsigned short h) {
  return __uint_as_float(((uint32_t)h) << 16);
}
__device__ __forceinline__ float bflo(uint32_t u) { return __uint_as_float(u << 16); }
__device__ __forceinline__ float bfhi(uint32_t u) { return __uint_as_float(u & 0xffff0000u); }

// ---------------- utility ----------------
__global__ void k_zero(int* __restrict__ p, int n) {
  int i = blockIdx.x * blockDim.x + threadIdx.x;
  if (i < n) p[i] = 0;
}

// ---------------- CSR build ----------------
__global__ void k_hist(const int* __restrict__ dst, int* __restrict__ cnt, int E) {
  int i = blockIdx.x * blockDim.x + threadIdx.x;
  if (i < E) atomicAdd(&cnt[dst[i]], 1);
}

__global__ __launch_bounds__(256) void k_scan_blk(const int* __restrict__ cnt,
                                                  int* __restrict__ rowp,
                                                  int* __restrict__ bsum,
                                                  float* __restrict__ dinv, int n) {
  __shared__ int wsum[4];
  const int tid = threadIdx.x, lane = tid & 63, wid = tid >> 6;
  const int base = blockIdx.x * 1024 + tid * 4;
  int v[4];
#pragma unroll
  for (int q = 0; q < 4; ++q) {
    int idx = base + q;
    v[q] = (idx < n) ? cnt[idx] : 0;
    if (idx < n) dinv[idx] = rsqrtf((float)(v[q] + 1));  // +1 self loop
  }
  int s = v[0] + v[1] + v[2] + v[3];
  int sc = s;
#pragma unroll
  for (int off = 1; off < 64; off <<= 1) {
    int t = __shfl_up(sc, off);
    if (lane >= off) sc += t;
  }
  if (lane == 63) wsum[wid] = sc;
  __syncthreads();
  int woff = 0;
#pragma unroll
  for (int w = 0; w < 4; ++w)
    if (w < wid) woff += wsum[w];
  int run = woff + sc - s;
#pragma unroll
  for (int q = 0; q < 4; ++q) {
    int idx = base + q;
    if (idx < n) rowp[idx] = run;
    run += v[q];
  }
  if (tid == 255) bsum[blockIdx.x] = woff + sc;
}

__global__ __launch_bounds__(256) void k_scan_top(int* __restrict__ bsum, int nb) {
  __shared__ int sm[256];
  const int tid = threadIdx.x;
  int v = (tid < nb) ? bsum[tid] : 0;
  sm[tid] = v;
  __syncthreads();
  for (int off = 1; off < 256; off <<= 1) {
    int t = (tid >= off) ? sm[tid - off] : 0;
    __syncthreads();
    sm[tid] += t;
    __syncthreads();
  }
  int incl = sm[tid];
  if (tid < nb) bsum[tid] = incl - v;
  if (tid == nb - 1) bsum[nb] = incl;
}

__global__ void k_scan_add(int* __restrict__ rowp, const int* __restrict__ bsum,
                           int n, int nb) {
  int i = blockIdx.x * blockDim.x + threadIdx.x;
  if (i < n) rowp[i] += bsum[i >> 10];
  if (i == 0) rowp[n] = bsum[nb];
}

__global__ void k_fill(const int* __restrict__ src, const int* __restrict__ dst,
                       const int* __restrict__ rowp, int* __restrict__ cur,
                       int* __restrict__ colsrc, int E) {
  int i = blockIdx.x * blockDim.x + threadIdx.x;
  if (i < E) {
    int d = dst[i];
    int pos = rowp[d] + atomicAdd(&cur[d], 1);
    colsrc[pos] = src[i];
  }
}

// ---------------- weight split (transposed hi/lo planes): Win, Wg1, Wg2 ----------------
__global__ void k_splitw_all(const float* __restrict__ Win, const float* __restrict__ Wg1,
                             const float* __restrict__ Wg2,
                             unsigned short* __restrict__ WinTh, unsigned short* __restrict__ WinTl,
                             unsigned short* __restrict__ Wg1Th, unsigned short* __restrict__ Wg1Tl,
                             unsigned short* __restrict__ Wg2Th, unsigned short* __restrict__ Wg2Tl) {
  int t = blockIdx.x * blockDim.x + threadIdx.x;
  const float* W;
  unsigned short *H, *L;
  int K, NC, r;
  if (t < 32768)      { W = Win; H = WinTh; L = WinTl; K = 256; NC = 128; r = t; }
  else if (t < 49152) { W = Wg1; H = Wg1Th; L = Wg1Tl; K = 128; NC = 128; r = t - 32768; }
  else if (t < 65536) { W = Wg2; H = Wg2Th; L = Wg2Tl; K = 128; NC = 128; r = t - 49152; }
  else return;
  int k = r / NC, n2 = r % NC;
  float v = W[t < 32768 ? r : (t < 49152 ? r : r)];
  v = W[r];
  unsigned short h = f2bf_rn(v);
  H[(size_t)n2 * K + k] = h;
  L[(size_t)n2 * K + k] = f2bf_rn(v - bf2f(h));
}

// ---------------- merged prep: waT logits-fold, V-fold planes, cbias ----------------
__global__ __launch_bounds__(256) void k_prep(const float* __restrict__ Wgat,
                                              const float* __restrict__ att_src,
                                              const float* __restrict__ att_dst,
                                              const float* __restrict__ Wao,
                                              const float* __restrict__ bgat,
                                              const float* __restrict__ bao,
                                              float* __restrict__ waT,
                                              unsigned short* __restrict__ VTh,
                                              unsigned short* __restrict__ VTl,
                                              float* __restrict__ cb) {
  int t = blockIdx.x * blockDim.x + threadIdx.x;
  if (t < 1024) {
    // waT[p][k]: p<4 src head p; p>=4 dst head p-4
    int p = t >> 7, k = t & 127;
    int h = p & 3;
    const float* av = (p < 4 ? att_src : att_dst) + h * HID;
    const float* wrow = Wgat + (size_t)k * GATD + h * HID;
    float s = 0.f;
#pragma unroll 4
    for (int c = 0; c < HID; ++c) s = fmaf(wrow[c], av[c], s);
    waT[t] = s;
  } else if (t < 1024 + 65536) {
    // VT[j][k], j = c*4+h head-interleaved: V = Wgat_h @ Wao_h folded
    int r = t - 1024;
    int j = r >> 7, k = r & 127;
    int c = j >> 2, h = j & 3;
    const float* wg = Wgat + (size_t)k * GATD + h * HID;
    const float* wa = Wao + (size_t)(h * HID) * HID + c;
    float s = 0.f;
#pragma unroll 4
    for (int d = 0; d < HID; ++d) s = fmaf(wg[d], wa[(size_t)d * HID], s);
    unsigned short hi = f2bf_rn(s);
    VTh[(size_t)j * HID + k] = hi;
    VTl[(size_t)j * HID + k] = f2bf_rn(s - bf2f(hi));
  } else if (t < 1024 + 65536 + 128) {
    // cb[c] = bao[c] + sum_d bgat[d]*Wao[d][c]
    int c = t - 1024 - 65536;
    float s = bao[c];
    for (int d = 0; d < GATD; ++d) s = fmaf(bgat[d], Wao[(size_t)d * HID + c], s);
    cb[c] = s;
  }
}

// ---------------- weight-stationary MFMA GEMM ----------------
// C = act(A @ W + bias); W as (BhT,BlT)[NC,KTOT] transposed hi/lo planes in LDS per chunk.
// AMODE 0: A = (Ah,Al) pre-split planes.  AMODE 1: Ah = fp32 A, split in registers.
// A*B ~= Ah*Bh + Ah*Bl + Al*Bh.  OUTM: 0=f32, 1=bf16, 2=hi/lo planes.
template <int KTOT, int KC, int NCB, bool RELU, bool BIAS, int OUTM, int AMODE>
__global__ __launch_bounds__(256) void k_gemm5(
    const unsigned short* __restrict__ Ah, const unsigned short* __restrict__ Al,
    const unsigned short* __restrict__ BhT, const unsigned short* __restrict__ BlT,
    const float* __restrict__ bias, void* __restrict__ Cv, void* __restrict__ Cv2,
    int M, int NC) {
  constexpr int NSUB = KC / 32;
  constexpr int NCHUNK = KTOT / KC;
  constexpr int NCF = NCB / 16;
  constexpr int UNITS = NSUB * 2 * 4 * NCB;
  __shared__ alignas(16) unsigned short Bs[NSUB][2][4][NCB][8];
  const int tid = threadIdx.x, lane = tid & 63, wid = tid >> 6;
  const int m0 = blockIdx.x * 64;
  const int n0 = blockIdx.y * NCB;
  const int fr = lane & 15, g = lane >> 4;
  const int arow = m0 + wid * 16 + fr;
  const bool aok = arow < M;
  const size_t abase = (size_t)arow * KTOT;

  f32x4 acc[NCF];
#pragma unroll
  for (int cf = 0; cf < NCF; ++cf) acc[cf] = (f32x4){0.f, 0.f, 0.f, 0.f};

  for (int c = 0; c < NCHUNK; ++c) {
    const int c0 = c * KC;
    if (c > 0) __syncthreads();
#pragma unroll
    for (int it = 0; it < UNITS / 256; ++it) {
      const int u = tid + it * 256;
      const int n = u % NCB;
      int rest = u / NCB;
      const int kg = rest & 3;
      rest >>= 2;
      const int p = rest & 1;
      const int sub = rest >> 1;
      const unsigned short* sp =
          (p ? BlT : BhT) + (size_t)(n0 + n) * KTOT + c0 + sub * 32 + kg * 8;
      *(uint4*)&Bs[sub][p][kg][n][0] = *(const uint4*)sp;
    }
    __syncthreads();
#pragma unroll
    for (int sub = 0; sub < NSUB; ++sub) {
      const int kb = c0 + sub * 32 + g * 8;
      bf16x8 a_h = {}, a_l = {};
      if (aok) {
        if (AMODE == 0) {
          a_h = *(const bf16x8*)(Ah + abase + kb);
          a_l = *(const bf16x8*)(Al + abase + kb);
        } else {
          const float* Af = (const float*)Ah + abase + kb;
          float4 q0 = *(const float4*)Af;
          float4 q1 = *(const float4*)(Af + 4);
          float av[8] = {q0.x, q0.y, q0.z, q0.w, q1.x, q1.y, q1.z, q1.w};
          union { bf16x8 v; uint32_t u4[4]; } Hu, Lu;
#pragma unroll
          for (int q = 0; q < 4; ++q) {
            unsigned short h0 = f2bf_rn(av[2 * q]);
            unsigned short h1 = f2bf_rn(av[2 * q + 1]);
            unsigned short l0 = f2bf_rn(av[2 * q] - bf2f(h0));
            unsigned short l1 = f2bf_rn(av[2 * q + 1] - bf2f(h1));
            Hu.u4[q] = (uint32_t)h0 | ((uint32_t)h1 << 16);
            Lu.u4[q] = (uint32_t)l0 | ((uint32_t)l1 << 16);
          }
          a_h = Hu.v;
          a_l = Lu.v;
        }
      }
#pragma unroll
      for (int cf = 0; cf < NCF; ++cf) {
        bf16x8 b_h = *(const bf16x8*)&Bs[sub][0][g][cf * 16 + fr][0];
        bf16x8 b_l = *(const bf16x8*)&Bs[sub][1][g][cf * 16 + fr][0];
        acc[cf] = __builtin_amdgcn_mfma_f32_16x16x32_bf16(a_h, b_h, acc[cf], 0, 0, 0);
        acc[cf] = __builtin_amdgcn_mfma_f32_16x16x32_bf16(a_h, b_l, acc[cf], 0, 0, 0);
        acc[cf] = __builtin_amdgcn_mfma_f32_16x16x32_bf16(a_l, b_h, acc[cf], 0, 0, 0);
      }
    }
  }
#pragma unroll
  for (int cf = 0; cf < NCF; ++cf) {
    const int col = n0 + cf * 16 + fr;
    const float bv = BIAS ? bias[col] : 0.f;
#pragma unroll
    for (int r = 0; r < 4; ++r) {
      const int grow = m0 + wid * 16 + g * 4 + r;
      if (grow < M) {
        float v = acc[cf][r] + bv;
        if (RELU) v = fmaxf(v, 0.f);
        const size_t idx = (size_t)grow * NC + col;
        if (OUTM == 0) {
          ((float*)Cv)[idx] = v;
        } else if (OUTM == 1) {
          ((unsigned short*)Cv)[idx] = f2bf_rn(v);
        } else {
          unsigned short h = f2bf_rn(v);
          ((unsigned short*)Cv)[idx] = h;
          ((unsigned short*)Cv2)[idx] = f2bf_rn(v - bf2f(h));
        }
      }
    }
  }
}

// ---------------- GCN aggregate (bf16 gather) + bias + LN + ReLU (+residual, +GAT logits) ----------------
template <bool L2>
__global__ __launch_bounds__(256) void k_gcn_agg(
    const unsigned short* __restrict__ xwb, const float* __restrict__ dinv,
    const int* __restrict__ rowp, const int* __restrict__ colsrc,
    const float* __restrict__ bias, const float* __restrict__ gamma,
    const float* __restrict__ beta,
    const unsigned short* __restrict__ resh, const unsigned short* __restrict__ resl,
    unsigned short* __restrict__ oh, unsigned short* __restrict__ ol,
    const float* __restrict__ waT, float* __restrict__ a_s, float* __restrict__ a_d,
    int n) {
  __shared__ float w[8][HID];
  if (L2) {
    for (int t = threadIdx.x; t < 8 * HID; t += 256) ((float*)w)[t] = waT[t];
    __syncthreads();
  }
  const int lane = threadIdx.x & 63;
  const int i = blockIdx.x * 4 + (threadIdx.x >> 6);
  if (i >= n) return;
  const float di = dinv[i];
  const int c = lane * 2;
  uint32_t v0 = *(const uint32_t*)(xwb + (size_t)i * HID + c);
  float a0 = bflo(v0) * di * di, a1 = bfhi(v0) * di * di;  // self loop
  float b0 = 0.f, b1 = 0.f;
  const int e0 = rowp[i], e1 = rowp[i + 1];
  int j = e0;
  for (; j + 7 < e1; j += 8) {
    int ss[8];
    float ww[8];
    uint32_t uu[8];
#pragma unroll
    for (int q = 0; q < 8; ++q) ss[q] = colsrc[j + q];
#pragma unroll
    for (int q = 0; q < 8; ++q) ww[q] = dinv[ss[q]] * di;
#pragma unroll
    for (int q = 0; q < 8; ++q) uu[q] = *(const uint32_t*)(xwb + (size_t)ss[q] * HID + c);
#pragma unroll
    for (int q = 0; q < 8; ++q) {
      if (q & 1) {
        b0 = fmaf(bflo(uu[q]), ww[q], b0);
        b1 = fmaf(bfhi(uu[q]), ww[q], b1);
      } else {
        a0 = fmaf(bflo(uu[q]), ww[q], a0);
        a1 = fmaf(bfhi(uu[q]), ww[q], a1);
      }
    }
  }
  for (; j < e1; ++j) {
    int s0 = colsrc[j];
    float w0 = dinv[s0] * di;
    uint32_t u0 = *(const uint32_t*)(xwb + (size_t)s0 * HID + c);
    a0 = fmaf(bflo(u0), w0, a0);
    a1 = fmaf(bfhi(u0), w0, a1);
  }
  a0 += b0;
  a1 += b1;
  a0 += bias[c];
  a1 += bias[c + 1];
  float s1 = a0 + a1, s2 = a0 * a0 + a1 * a1;
#pragma unroll
  for (int m = 32; m >= 1; m >>= 1) {
    s1 += __shfl_xor(s1, m);
    s2 += __shfl_xor(s2, m);
  }
  float mu = s1 * (1.0f / HID);
  float var = s2 * (1.0f / HID) - mu * mu;
  float rstd = rsqrtf(var + 1e-5f);
  float y0 = fmaxf((a0 - mu) * rstd * gamma[c] + beta[c], 0.0f);
  float y1 = fmaxf((a1 - mu) * rstd * gamma[c + 1] + beta[c + 1], 0.0f);
  if (L2) {
    uint32_t rh = *(const uint32_t*)(resh + (size_t)i * HID + c);
    uint32_t rl = *(const uint32_t*)(resl + (size_t)i * HID + c);
    y0 += bflo(rh) + bflo(rl);
    y1 += bfhi(rh) + bfhi(rl);
  }
  unsigned short ph0 = f2bf_rn(y0), ph1 = f2bf_rn(y1);
  uint32_t hw = (uint32_t)ph0 | ((uint32_t)ph1 << 16);
  uint32_t lw = (uint32_t)f2bf_rn(y0 - bf2f(ph0)) |
                ((uint32_t)f2bf_rn(y1 - bf2f(ph1)) << 16);
  *(uint32_t*)(oh + (size_t)i * HID + c) = hw;
  *(uint32_t*)(ol + (size_t)i * HID + c) = lw;
  if (L2) {
    float p[8];
#pragma unroll
    for (int h = 0; h < 8; ++h) p[h] = y0 * w[h][c] + y1 * w[h][c + 1];
#pragma unroll
    for (int m = 32; m >= 1; m >>= 1) {
#pragma unroll
      for (int h = 0; h < 8; ++h) p[h] += __shfl_xor(p[h], m);
    }
    if (lane == 0) {
      a_s[i * 4 + 0] = p[0]; a_s[i * 4 + 1] = p[1];
      a_s[i * 4 + 2] = p[2]; a_s[i * 4 + 3] = p[3];
      a_d[i * 4 + 0] = p[4]; a_d[i * 4 + 1] = p[5];
      a_d[i * 4 + 2] = p[6]; a_d[i * 4 + 3] = p[7];
    }
  }
}

// ---------------- GAT softmax-aggregate on folded z + LDS-staged Wout epilogue -> d_out ----------------
// z row layout: elem c*4+h (head-interleaved). att = relu(sum_h agg_h + cb);
// out[i][cp] = bout[cp] + sum_c att[c] * Wout[c][cp], Wout staged in LDS.
__global__ __launch_bounds__(256) void k_gat_agg3(const unsigned short* __restrict__ zb,
                                                  const float* __restrict__ a_s,
                                                  const float* __restrict__ a_d,
                                                  const int* __restrict__ rowp,
                                                  const int* __restrict__ colsrc,
                                                  const float* __restrict__ cb,
                                                  const float* __restrict__ Wout,
                                                  const float* __restrict__ bout,
                                                  float* __restrict__ outp,
                                                  int n) {
  __shared__ float4 albuf[4][64];
  __shared__ int sbuf[4][64];
  __shared__ float attbuf[4][HID];
  __shared__ float Wlds[HID * 64];  // Wout natural layout [c][cp], 32 KB
  // stage Wout cooperatively (coalesced), before any divergence/return
  for (int t = threadIdx.x; t < HID * 64 / 4; t += 256)
    *(float4*)&Wlds[t * 4] = *(const float4*)&Wout[t * 4];
  __syncthreads();
  const int lane = threadIdx.x & 63;
  const int wid = threadIdx.x >> 6;
  const int i = blockIdx.x * 4 + wid;
  if (i >= n) return;
  const float4 adv = *(const float4*)(a_d + i * 4);
  const float4 asv = *(const float4*)(a_s + i * 4);
  float es0 = lrelu02(asv.x + adv.x);
  float es1 = lrelu02(asv.y + adv.y);
  float es2 = lrelu02(asv.z + adv.z);
  float es3 = lrelu02(asv.w + adv.w);
  const int e0 = rowp[i], e1 = rowp[i + 1];
  // pass 1: max
  float m0 = es0, m1 = es1, m2 = es2, m3 = es3;
  for (int j = e0 + lane; j < e1; j += 64) {
    int s = colsrc[j];
    const float4 av = *(const float4*)(a_s + s * 4);
    m0 = fmaxf(m0, lrelu02(av.x + adv.x));
    m1 = fmaxf(m1, lrelu02(av.y + adv.y));
    m2 = fmaxf(m2, lrelu02(av.z + adv.z));
    m3 = fmaxf(m3, lrelu02(av.w + adv.w));
  }
#pragma unroll
  for (int m = 32; m >= 1; m >>= 1) {
    m0 = fmaxf(m0, __shfl_xor(m0, m));
    m1 = fmaxf(m1, __shfl_xor(m1, m));
    m2 = fmaxf(m2, __shfl_xor(m2, m));
    m3 = fmaxf(m3, __shfl_xor(m3, m));
  }
  // pass 2: denom
  float d0 = 0.f, d1 = 0.f, d2 = 0.f, d3 = 0.f;
  for (int j = e0 + lane; j < e1; j += 64) {
    int s = colsrc[j];
    const float4 av = *(const float4*)(a_s + s * 4);
    d0 += __expf(lrelu02(av.x + adv.x) - m0);
    d1 += __expf(lrelu02(av.y + adv.y) - m1);
    d2 += __expf(lrelu02(av.z + adv.z) - m2);
    d3 += __expf(lrelu02(av.w + adv.w) - m3);
  }
#pragma unroll
  for (int m = 32; m >= 1; m >>= 1) {
    d0 += __shfl_xor(d0, m);
    d1 += __shfl_xor(d1, m);
    d2 += __shfl_xor(d2, m);
    d3 += __shfl_xor(d3, m);
  }
  d0 += __expf(es0 - m0);
  d1 += __expf(es1 - m1);
  d2 += __expf(es2 - m2);
  d3 += __expf(es3 - m3);
  const float inv0 = 1.0f / d0, inv1 = 1.0f / d1, inv2 = 1.0f / d2, inv3 = 1.0f / d3;
  const float4 asf = make_float4(__expf(es0 - m0) * inv0, __expf(es1 - m1) * inv1,
                                 __expf(es2 - m2) * inv2, __expf(es3 - m3) * inv3);
  const int col8 = lane * 8;  // elems [lane*8, lane*8+8): c0=lane*2 (h0..3), c0+1 (h0..3)
  uint4 u = *(const uint4*)(zb + (size_t)i * GATD + col8);
  float4 accC0 = make_float4(bflo(u.x) * asf.x, bfhi(u.x) * asf.y,
                             bflo(u.y) * asf.z, bfhi(u.y) * asf.w);
  float4 accC1 = make_float4(bflo(u.z) * asf.x, bfhi(u.z) * asf.y,
                             bflo(u.w) * asf.z, bfhi(u.w) * asf.w);
  // pass 3: chunked -- 64 lanes compute 64 edge-alphas, then all lanes stream messages
  for (int b = e0; b < e1; b += 64) {
    int j = b + lane;
    if (j < e1) {
      int s = colsrc[j];
      const float4 av = *(const float4*)(a_s + s * 4);
      albuf[wid][lane] = make_float4(__expf(lrelu02(av.x + adv.x) - m0) * inv0,
                                     __expf(lrelu02(av.y + adv.y) - m1) * inv1,
                                     __expf(lrelu02(av.z + adv.z) - m2) * inv2,
                                     __expf(lrelu02(av.w + adv.w) - m3) * inv3);
      sbuf[wid][lane] = s;
    }
    asm volatile("s_waitcnt lgkmcnt(0)" ::: "memory");
    const int cnt = min(64, e1 - b);
    for (int t = 0; t < cnt; ++t) {
      float4 a4 = albuf[wid][t];
      int s = sbuf[wid][t];
      uint4 w = *(const uint4*)(zb + (size_t)s * GATD + col8);
      accC0.x = fmaf(bflo(w.x), a4.x, accC0.x);
      accC0.y = fmaf(bfhi(w.x), a4.y, accC0.y);
      accC0.z = fmaf(bflo(w.y), a4.z, accC0.z);
      accC0.w = fmaf(bfhi(w.y), a4.w, accC0.w);
      accC1.x = fmaf(bflo(w.z), a4.x, accC1.x);
      accC1.y = fmaf(bfhi(w.z), a4.y, accC1.y);
      accC1.z = fmaf(bflo(w.w), a4.z, accC1.z);
      accC1.w = fmaf(bfhi(w.w), a4.w, accC1.w);
    }
  }
  const int c0 = lane * 2;
  float2 cbv = *(const float2*)(cb + c0);
  float o0 = fmaxf(accC0.x + accC0.y + accC0.z + accC0.w + cbv.x, 0.0f);
  float o1 = fmaxf(accC1.x + accC1.y + accC1.z + accC1.w + cbv.y, 0.0f);
  // fused Wout epilogue from LDS: lane owns out col `lane`; Wlds[c*64+lane] is 2-way free
  attbuf[wid][c0] = o0;
  attbuf[wid][c0 + 1] = o1;
  asm volatile("s_waitcnt lgkmcnt(0)" ::: "memory");
  float acc = bout[lane];
#pragma unroll 16
  for (int c = 0; c < HID; ++c) acc = fmaf(attbuf[wid][c], Wlds[c * 64 + lane], acc);
  outp[(size_t)i * 64 + lane] = acc;
}

extern "C" void kernel_launch(void* const* d_in, const int* in_sizes, int n_in,
                              void* d_out, int out_size, void* d_ws, size_t ws_size,
                              hipStream_t stream) {
  const float* x = (const float*)d_in[0];
  const int* ei = (const int*)d_in[1];
  const float* Win = (const float*)d_in[2];
  const float* bin = (const float*)d_in[3];
  const float* Wg1 = (const float*)d_in[4];
  const float* bg1 = (const float*)d_in[5];
  const float* g1g = (const float*)d_in[6];
  const float* g1b = (const float*)d_in[7];
  const float* Wg2 = (const float*)d_in[8];
  const float* bg2 = (const float*)d_in[9];
  const float* g2g = (const float*)d_in[10];
  const float* g2b = (const float*)d_in[11];
  const float* Wgat = (const float*)d_in[12];
  const float* att_s = (const float*)d_in[13];
  const float* att_d = (const float*)d_in[14];
  const float* bgat = (const float*)d_in[15];
  const float* Wao = (const float*)d_in[16];
  const float* bao = (const float*)d_in[17];
  const float* Wout = (const float*)d_in[18];
  const float* bout = (const float*)d_in[19];

  const int N = in_sizes[0] / 256;
  const int E = in_sizes[1] / 2;
  const int* src = ei;
  const int* dst = ei + E;

  // ---- workspace layout (bytes), ~145 MB ----
  char* base = (char*)d_ws;
  size_t off = 0;
  unsigned short* h0h = (unsigned short*)(base + off); off += (size_t)N * HID * 2;
  unsigned short* h0l = (unsigned short*)(base + off); off += (size_t)N * HID * 2;
  unsigned short* x1h = (unsigned short*)(base + off); off += (size_t)N * HID * 2;
  unsigned short* x1l = (unsigned short*)(base + off); off += (size_t)N * HID * 2;
  unsigned short* xwb = (unsigned short*)(base + off); off += (size_t)N * HID * 2;
  unsigned short* x2h = (unsigned short*)(base + off); off += (size_t)N * HID * 2;
  unsigned short* x2l = (unsigned short*)(base + off); off += (size_t)N * HID * 2;
  unsigned short* zb = (unsigned short*)(base + off); off += (size_t)N * GATD * 2;
  float* dinv = (float*)(base + off);                 off += (size_t)N * 4;
  float* a_s = (float*)(base + off);                  off += (size_t)N * 16;
  float* a_d = (float*)(base + off);                  off += (size_t)N * 16;
  float* waT = (float*)(base + off);                  off += 4096;
  float* cb = (float*)(base + off);                   off += 512;
  unsigned short *WinTh, *WinTl, *Wg1Th, *Wg1Tl, *Wg2Th, *Wg2Tl, *VTh, *VTl;
  WinTh = (unsigned short*)(base + off); off += 256 * 128 * 2;
  WinTl = (unsigned short*)(base + off); off += 256 * 128 * 2;
  Wg1Th = (unsigned short*)(base + off); off += 128 * 128 * 2;
  Wg1Tl = (unsigned short*)(base + off); off += 128 * 128 * 2;
  Wg2Th = (unsigned short*)(base + off); off += 128 * 128 * 2;
  Wg2Tl = (unsigned short*)(base + off); off += 128 * 128 * 2;
  VTh = (unsigned short*)(base + off);   off += 512 * 128 * 2;
  VTl = (unsigned short*)(base + off);   off += 512 * 128 * 2;
  int* rowp = (int*)(base + off);   off += (size_t)(N + 1) * 4;
  int* colsrc = (int*)(base + off); off += (size_t)E * 4;
  const int nb2 = (N + 1023) / 1024;
  int* bsum = (int*)(base + off);   off += (size_t)(nb2 + 2) * 4;
  int* cnt = (int*)zb;  // alias: dead before zb is written
  int* cur = cnt + N;

  const int eb = (E + TPB - 1) / TPB;
  const int zbk = (2 * N + TPB - 1) / TPB;
  const int ab = (N + 3) / 4;
  const int gm = (N + 63) / 64;

  // CSR + prep
  k_zero<<<zbk, TPB, 0, stream>>>(cnt, 2 * N);
  k_hist<<<eb, TPB, 0, stream>>>(dst, cnt, E);
  k_scan_blk<<<nb2, 256, 0, stream>>>(cnt, rowp, bsum, dinv, N);
  k_scan_top<<<1, 256, 0, stream>>>(bsum, nb2);
  k_scan_add<<<(N + 255) / 256, 256, 0, stream>>>(rowp, bsum, N, nb2);
  k_fill<<<eb, TPB, 0, stream>>>(src, dst, rowp, cur, colsrc, E);
  k_prep<<<(1024 + 65536 + 128 + 255) / 256, 256, 0, stream>>>(
      Wgat, att_s, att_d, Wao, bgat, bao, waT, VTh, VTl, cb);
  k_splitw_all<<<(65536 + 255) / 256, 256, 0, stream>>>(
      Win, Wg1, Wg2, WinTh, WinTl, Wg1Th, Wg1Tl, Wg2Th, Wg2Tl);

  // h0 = relu(x @ Win + bin) -> planes    [fp32 A split in regs]
  k_gemm5<256, 64, 128, true, true, 2, 1><<<dim3(gm, 1), 256, 0, stream>>>(
      (const unsigned short*)x, nullptr, WinTh, WinTl, bin, h0h, h0l, N, 128);
  // GCN layer 1: xwb = bf16(h0 @ Wg1)
  k_gemm5<128, 64, 128, false, false, 1, 0><<<dim3(gm, 1), 256, 0, stream>>>(
      h0h, h0l, Wg1Th, Wg1Tl, nullptr, xwb, nullptr, N, 128);
  k_gcn_agg<false><<<ab, 256, 0, stream>>>(xwb, dinv, rowp, colsrc, bg1, g1g, g1b,
                                           nullptr, nullptr, x1h, x1l,
                                           nullptr, nullptr, nullptr, N);
  // GCN layer 2 (+residual, +fused GAT logits)
  k_gemm5<128, 64, 128, false, false, 1, 0><<<dim3(gm, 1), 256, 0, stream>>>(
      x1h, x1l, Wg2Th, Wg2Tl, nullptr, xwb, nullptr, N, 128);
  k_gcn_agg<true><<<ab, 256, 0, stream>>>(xwb, dinv, rowp, colsrc, bg2, g2g, g2b,
                                          x1h, x1l, x2h, x2l, waT, a_s, a_d, N);
  // z = bf16(x2 @ V)  [head-interleaved cols; NCB=256, KC=32, y=2]
  k_gemm5<128, 32, 256, false, false, 1, 0><<<dim3(gm, 2), 256, 0, stream>>>(
      x2h, x2l, VTh, VTl, nullptr, zb, nullptr, N, 512);
  // softmax-aggregate on z + LDS-staged Wout epilogue -> d_out directly
  k_gat_agg3<<<ab, 256, 0, stream>>>(zb, a_s, a_d, rowp, colsrc, cb, Wout, bout,
                                     (float*)d_out, N);
}

// Round 14
// 483.305 us; speedup vs baseline: 1.1817x; 1.0112x over previous
//
#include <hip/hip_runtime.h>
#include <hip/hip_bf16.h>
#include <cstddef>
#include <cstdint>

#define TPB 256
#define HID 128
#define GATD 512
#define HEADS 4

typedef __attribute__((ext_vector_type(8))) short bf16x8;
typedef __attribute__((ext_vector_type(4))) float f32x4;

__device__ __forceinline__ float lrelu02(float x) { return x > 0.0f ? x : 0.2f * x; }

__device__ __forceinline__ unsigned short f2bf_rn(float f) {
  uint32_t u = __float_as_uint(f);
  u += 0x7fff + ((u >> 16) & 1);
  return (unsigned short)(u >> 16);
}
__device__ __forceinline__ float bf2f(unsigned short h) {
  return __uint_as_float(((uint32_t)h) << 16);
}
__device__ __forceinline__ float bflo(uint32_t u) { return __uint_as_float(u << 16); }
__device__ __forceinline__ float bfhi(uint32_t u) { return __uint_as_float(u & 0xffff0000u); }

// ---------------- utility ----------------
__global__ void k_zero(int* __restrict__ p, int n) {
  int i = blockIdx.x * blockDim.x + threadIdx.x;
  if (i < n) p[i] = 0;
}

// ---------------- CSR build ----------------
__global__ void k_hist(const int* __restrict__ dst, int* __restrict__ cnt, int E) {
  int i = blockIdx.x * blockDim.x + threadIdx.x;
  if (i < E) atomicAdd(&cnt[dst[i]], 1);
}

__global__ __launch_bounds__(256) void k_scan_blk(const int* __restrict__ cnt,
                                                  int* __restrict__ rowp,
                                                  int* __restrict__ bsum,
                                                  float* __restrict__ dinv, int n) {
  __shared__ int wsum[4];
  const int tid = threadIdx.x, lane = tid & 63, wid = tid >> 6;
  const int base = blockIdx.x * 1024 + tid * 4;
  int v[4];
#pragma unroll
  for (int q = 0; q < 4; ++q) {
    int idx = base + q;
    v[q] = (idx < n) ? cnt[idx] : 0;
    if (idx < n) dinv[idx] = rsqrtf((float)(v[q] + 1));  // +1 self loop
  }
  int s = v[0] + v[1] + v[2] + v[3];
  int sc = s;
#pragma unroll
  for (int off = 1; off < 64; off <<= 1) {
    int t = __shfl_up(sc, off);
    if (lane >= off) sc += t;
  }
  if (lane == 63) wsum[wid] = sc;
  __syncthreads();
  int woff = 0;
#pragma unroll
  for (int w = 0; w < 4; ++w)
    if (w < wid) woff += wsum[w];
  int run = woff + sc - s;
#pragma unroll
  for (int q = 0; q < 4; ++q) {
    int idx = base + q;
    if (idx < n) rowp[idx] = run;
    run += v[q];
  }
  if (tid == 255) bsum[blockIdx.x] = woff + sc;
}

__global__ __launch_bounds__(256) void k_scan_top(int* __restrict__ bsum, int nb) {
  __shared__ int sm[256];
  const int tid = threadIdx.x;
  int v = (tid < nb) ? bsum[tid] : 0;
  sm[tid] = v;
  __syncthreads();
  for (int off = 1; off < 256; off <<= 1) {
    int t = (tid >= off) ? sm[tid - off] : 0;
    __syncthreads();
    sm[tid] += t;
    __syncthreads();
  }
  int incl = sm[tid];
  if (tid < nb) bsum[tid] = incl - v;
  if (tid == nb - 1) bsum[nb] = incl;
}

__global__ void k_scan_add(int* __restrict__ rowp, const int* __restrict__ bsum,
                           int n, int nb) {
  int i = blockIdx.x * blockDim.x + threadIdx.x;
  if (i < n) rowp[i] += bsum[i >> 10];
  if (i == 0) rowp[n] = bsum[nb];
}

__global__ void k_fill(const int* __restrict__ src, const int* __restrict__ dst,
                       const int* __restrict__ rowp, int* __restrict__ cur,
                       int* __restrict__ colsrc, int E) {
  int i = blockIdx.x * blockDim.x + threadIdx.x;
  if (i < E) {
    int d = dst[i];
    int pos = rowp[d] + atomicAdd(&cur[d], 1);
    colsrc[pos] = src[i];
  }
}

// ---------------- weight split (transposed hi/lo planes): Win, Wg1, Wg2 ----------------
__global__ void k_splitw_all(const float* __restrict__ Win, const float* __restrict__ Wg1,
                             const float* __restrict__ Wg2,
                             unsigned short* __restrict__ WinTh, unsigned short* __restrict__ WinTl,
                             unsigned short* __restrict__ Wg1Th, unsigned short* __restrict__ Wg1Tl,
                             unsigned short* __restrict__ Wg2Th, unsigned short* __restrict__ Wg2Tl) {
  int t = blockIdx.x * blockDim.x + threadIdx.x;
  const float* W;
  unsigned short *H, *L;
  int K, NC, r;
  if (t < 32768)      { W = Win; H = WinTh; L = WinTl; K = 256; NC = 128; r = t; }
  else if (t < 49152) { W = Wg1; H = Wg1Th; L = Wg1Tl; K = 128; NC = 128; r = t - 32768; }
  else if (t < 65536) { W = Wg2; H = Wg2Th; L = Wg2Tl; K = 128; NC = 128; r = t - 49152; }
  else return;
  int k = r / NC, n2 = r % NC;
  float v = W[r];
  unsigned short h = f2bf_rn(v);
  H[(size_t)n2 * K + k] = h;
  L[(size_t)n2 * K + k] = f2bf_rn(v - bf2f(h));
}

// ---------------- merged prep: waT logits-fold, V-fold planes, cbias ----------------
__global__ __launch_bounds__(256) void k_prep(const float* __restrict__ Wgat,
                                              const float* __restrict__ att_src,
                                              const float* __restrict__ att_dst,
                                              const float* __restrict__ Wao,
                                              const float* __restrict__ bgat,
                                              const float* __restrict__ bao,
                                              float* __restrict__ waT,
                                              unsigned short* __restrict__ VTh,
                                              unsigned short* __restrict__ VTl,
                                              float* __restrict__ cb) {
  int t = blockIdx.x * blockDim.x + threadIdx.x;
  if (t < 1024) {
    // waT[p][k]: p<4 src head p; p>=4 dst head p-4
    int p = t >> 7, k = t & 127;
    int h = p & 3;
    const float* av = (p < 4 ? att_src : att_dst) + h * HID;
    const float* wrow = Wgat + (size_t)k * GATD + h * HID;
    float s = 0.f;
#pragma unroll 4
    for (int c = 0; c < HID; ++c) s = fmaf(wrow[c], av[c], s);
    waT[t] = s;
  } else if (t < 1024 + 65536) {
    // VT[j][k], j = c*4+h head-interleaved: V = Wgat_h @ Wao_h folded
    int r = t - 1024;
    int j = r >> 7, k = r & 127;
    int c = j >> 2, h = j & 3;
    const float* wg = Wgat + (size_t)k * GATD + h * HID;
    const float* wa = Wao + (size_t)(h * HID) * HID + c;
    float s = 0.f;
#pragma unroll 4
    for (int d = 0; d < HID; ++d) s = fmaf(wg[d], wa[(size_t)d * HID], s);
    unsigned short hi = f2bf_rn(s);
    VTh[(size_t)j * HID + k] = hi;
    VTl[(size_t)j * HID + k] = f2bf_rn(s - bf2f(hi));
  } else if (t < 1024 + 65536 + 128) {
    // cb[c] = bao[c] + sum_d bgat[d]*Wao[d][c]
    int c = t - 1024 - 65536;
    float s = bao[c];
    for (int d = 0; d < GATD; ++d) s = fmaf(bgat[d], Wao[(size_t)d * HID + c], s);
    cb[c] = s;
  }
}

// ---------------- weight-stationary MFMA GEMM ----------------
// C = act(A @ W + bias); W as (BhT,BlT)[NC,KTOT] transposed hi/lo planes in LDS per chunk.
// AMODE 0: A = (Ah,Al) pre-split planes.  AMODE 1: Ah = fp32 A, split in registers.
// A*B ~= Ah*Bh + Ah*Bl + Al*Bh.  OUTM: 0=f32, 1=bf16, 2=hi/lo planes.
template <int KTOT, int KC, int NCB, bool RELU, bool BIAS, int OUTM, int AMODE>
__global__ __launch_bounds__(256) void k_gemm5(
    const unsigned short* __restrict__ Ah, const unsigned short* __restrict__ Al,
    const unsigned short* __restrict__ BhT, const unsigned short* __restrict__ BlT,
    const float* __restrict__ bias, void* __restrict__ Cv, void* __restrict__ Cv2,
    int M, int NC) {
  constexpr int NSUB = KC / 32;
  constexpr int NCHUNK = KTOT / KC;
  constexpr int NCF = NCB / 16;
  constexpr int UNITS = NSUB * 2 * 4 * NCB;
  __shared__ alignas(16) unsigned short Bs[NSUB][2][4][NCB][8];
  const int tid = threadIdx.x, lane = tid & 63, wid = tid >> 6;
  const int m0 = blockIdx.x * 64;
  const int n0 = blockIdx.y * NCB;
  const int fr = lane & 15, g = lane >> 4;
  const int arow = m0 + wid * 16 + fr;
  const bool aok = arow < M;
  const size_t abase = (size_t)arow * KTOT;

  f32x4 acc[NCF];
#pragma unroll
  for (int cf = 0; cf < NCF; ++cf) acc[cf] = (f32x4){0.f, 0.f, 0.f, 0.f};

  for (int c = 0; c < NCHUNK; ++c) {
    const int c0 = c * KC;
    if (c > 0) __syncthreads();
#pragma unroll
    for (int it = 0; it < UNITS / 256; ++it) {
      const int u = tid + it * 256;
      const int n = u % NCB;
      int rest = u / NCB;
      const int kg = rest & 3;
      rest >>= 2;
      const int p = rest & 1;
      const int sub = rest >> 1;
      const unsigned short* sp =
          (p ? BlT : BhT) + (size_t)(n0 + n) * KTOT + c0 + sub * 32 + kg * 8;
      *(uint4*)&Bs[sub][p][kg][n][0] = *(const uint4*)sp;
    }
    __syncthreads();
#pragma unroll
    for (int sub = 0; sub < NSUB; ++sub) {
      const int kb = c0 + sub * 32 + g * 8;
      bf16x8 a_h = {}, a_l = {};
      if (aok) {
        if (AMODE == 0) {
          a_h = *(const bf16x8*)(Ah + abase + kb);
          a_l = *(const bf16x8*)(Al + abase + kb);
        } else {
          const float* Af = (const float*)Ah + abase + kb;
          float4 q0 = *(const float4*)Af;
          float4 q1 = *(const float4*)(Af + 4);
          float av[8] = {q0.x, q0.y, q0.z, q0.w, q1.x, q1.y, q1.z, q1.w};
          union { bf16x8 v; uint32_t u4[4]; } Hu, Lu;
#pragma unroll
          for (int q = 0; q < 4; ++q) {
            unsigned short h0 = f2bf_rn(av[2 * q]);
            unsigned short h1 = f2bf_rn(av[2 * q + 1]);
            unsigned short l0 = f2bf_rn(av[2 * q] - bf2f(h0));
            unsigned short l1 = f2bf_rn(av[2 * q + 1] - bf2f(h1));
            Hu.u4[q] = (uint32_t)h0 | ((uint32_t)h1 << 16);
            Lu.u4[q] = (uint32_t)l0 | ((uint32_t)l1 << 16);
          }
          a_h = Hu.v;
          a_l = Lu.v;
        }
      }
#pragma unroll
      for (int cf = 0; cf < NCF; ++cf) {
        bf16x8 b_h = *(const bf16x8*)&Bs[sub][0][g][cf * 16 + fr][0];
        bf16x8 b_l = *(const bf16x8*)&Bs[sub][1][g][cf * 16 + fr][0];
        acc[cf] = __builtin_amdgcn_mfma_f32_16x16x32_bf16(a_h, b_h, acc[cf], 0, 0, 0);
        acc[cf] = __builtin_amdgcn_mfma_f32_16x16x32_bf16(a_h, b_l, acc[cf], 0, 0, 0);
        acc[cf] = __builtin_amdgcn_mfma_f32_16x16x32_bf16(a_l, b_h, acc[cf], 0, 0, 0);
      }
    }
  }
#pragma unroll
  for (int cf = 0; cf < NCF; ++cf) {
    const int col = n0 + cf * 16 + fr;
    const float bv = BIAS ? bias[col] : 0.f;
#pragma unroll
    for (int r = 0; r < 4; ++r) {
      const int grow = m0 + wid * 16 + g * 4 + r;
      if (grow < M) {
        float v = acc[cf][r] + bv;
        if (RELU) v = fmaxf(v, 0.f);
        const size_t idx = (size_t)grow * NC + col;
        if (OUTM == 0) {
          ((float*)Cv)[idx] = v;
        } else if (OUTM == 1) {
          ((unsigned short*)Cv)[idx] = f2bf_rn(v);
        } else {
          unsigned short h = f2bf_rn(v);
          ((unsigned short*)Cv)[idx] = h;
          ((unsigned short*)Cv2)[idx] = f2bf_rn(v - bf2f(h));
        }
      }
    }
  }
}

// ---------------- GCN aggregate (bf16 gather) + bias + LN + ReLU (+residual, +GAT logits) ----------------
template <bool L2>
__global__ __launch_bounds__(256) void k_gcn_agg(
    const unsigned short* __restrict__ xwb, const float* __restrict__ dinv,
    const int* __restrict__ rowp, const int* __restrict__ colsrc,
    const float* __restrict__ bias, const float* __restrict__ gamma,
    const float* __restrict__ beta,
    const unsigned short* __restrict__ resh, const unsigned short* __restrict__ resl,
    unsigned short* __restrict__ oh, unsigned short* __restrict__ ol,
    const float* __restrict__ waT, float* __restrict__ a_s, float* __restrict__ a_d,
    int n) {
  __shared__ float w[8][HID];
  if (L2) {
    for (int t = threadIdx.x; t < 8 * HID; t += 256) ((float*)w)[t] = waT[t];
    __syncthreads();
  }
  const int lane = threadIdx.x & 63;
  const int i = blockIdx.x * 4 + (threadIdx.x >> 6);
  if (i >= n) return;
  const float di = dinv[i];
  const int c = lane * 2;
  uint32_t v0 = *(const uint32_t*)(xwb + (size_t)i * HID + c);
  float a0 = bflo(v0) * di * di, a1 = bfhi(v0) * di * di;  // self loop
  float b0 = 0.f, b1 = 0.f;
  const int e0 = rowp[i], e1 = rowp[i + 1];
  int j = e0;
  for (; j + 7 < e1; j += 8) {
    int ss[8];
    float ww[8];
    uint32_t uu[8];
#pragma unroll
    for (int q = 0; q < 8; ++q) ss[q] = colsrc[j + q];
#pragma unroll
    for (int q = 0; q < 8; ++q) ww[q] = dinv[ss[q]] * di;
#pragma unroll
    for (int q = 0; q < 8; ++q) uu[q] = *(const uint32_t*)(xwb + (size_t)ss[q] * HID + c);
#pragma unroll
    for (int q = 0; q < 8; ++q) {
      if (q & 1) {
        b0 = fmaf(bflo(uu[q]), ww[q], b0);
        b1 = fmaf(bfhi(uu[q]), ww[q], b1);
      } else {
        a0 = fmaf(bflo(uu[q]), ww[q], a0);
        a1 = fmaf(bfhi(uu[q]), ww[q], a1);
      }
    }
  }
  for (; j < e1; ++j) {
    int s0 = colsrc[j];
    float w0 = dinv[s0] * di;
    uint32_t u0 = *(const uint32_t*)(xwb + (size_t)s0 * HID + c);
    a0 = fmaf(bflo(u0), w0, a0);
    a1 = fmaf(bfhi(u0), w0, a1);
  }
  a0 += b0;
  a1 += b1;
  a0 += bias[c];
  a1 += bias[c + 1];
  float s1 = a0 + a1, s2 = a0 * a0 + a1 * a1;
#pragma unroll
  for (int m = 32; m >= 1; m >>= 1) {
    s1 += __shfl_xor(s1, m);
    s2 += __shfl_xor(s2, m);
  }
  float mu = s1 * (1.0f / HID);
  float var = s2 * (1.0f / HID) - mu * mu;
  float rstd = rsqrtf(var + 1e-5f);
  float y0 = fmaxf((a0 - mu) * rstd * gamma[c] + beta[c], 0.0f);
  float y1 = fmaxf((a1 - mu) * rstd * gamma[c + 1] + beta[c + 1], 0.0f);
  if (L2) {
    uint32_t rh = *(const uint32_t*)(resh + (size_t)i * HID + c);
    uint32_t rl = *(const uint32_t*)(resl + (size_t)i * HID + c);
    y0 += bflo(rh) + bflo(rl);
    y1 += bfhi(rh) + bfhi(rl);
  }
  unsigned short ph0 = f2bf_rn(y0), ph1 = f2bf_rn(y1);
  uint32_t hw = (uint32_t)ph0 | ((uint32_t)ph1 << 16);
  uint32_t lw = (uint32_t)f2bf_rn(y0 - bf2f(ph0)) |
                ((uint32_t)f2bf_rn(y1 - bf2f(ph1)) << 16);
  *(uint32_t*)(oh + (size_t)i * HID + c) = hw;
  *(uint32_t*)(ol + (size_t)i * HID + c) = lw;
  if (L2) {
    float p[8];
#pragma unroll
    for (int h = 0; h < 8; ++h) p[h] = y0 * w[h][c] + y1 * w[h][c + 1];
#pragma unroll
    for (int m = 32; m >= 1; m >>= 1) {
#pragma unroll
      for (int h = 0; h < 8; ++h) p[h] += __shfl_xor(p[h], m);
    }
    if (lane == 0) {
      a_s[i * 4 + 0] = p[0]; a_s[i * 4 + 1] = p[1];
      a_s[i * 4 + 2] = p[2]; a_s[i * 4 + 3] = p[3];
      a_d[i * 4 + 0] = p[4]; a_d[i * 4 + 1] = p[5];
      a_d[i * 4 + 2] = p[6]; a_d[i * 4 + 3] = p[7];
    }
  }
}

// ---------------- GAT softmax-aggregate on folded z + LDS-staged Wout epilogue -> d_out ----------------
// 512-thread blocks: 8 waves = 8 nodes/block, Wout LDS copy amortized 2x, 24 waves/CU.
__global__ __launch_bounds__(512) void k_gat_agg3(const unsigned short* __restrict__ zb,
                                                  const float* __restrict__ a_s,
                                                  const float* __restrict__ a_d,
                                                  const int* __restrict__ rowp,
                                                  const int* __restrict__ colsrc,
                                                  const float* __restrict__ cb,
                                                  const float* __restrict__ Wout,
                                                  const float* __restrict__ bout,
                                                  float* __restrict__ outp,
                                                  int n) {
  __shared__ float4 albuf[8][64];
  __shared__ int sbuf[8][64];
  __shared__ float attbuf[8][HID];
  __shared__ float Wlds[HID * 64];  // Wout natural layout [c][cp], 32 KB
  // stage Wout cooperatively (coalesced), before any divergence/return
  for (int t = threadIdx.x; t < HID * 64 / 4; t += 512)
    *(float4*)&Wlds[t * 4] = *(const float4*)&Wout[t * 4];
  __syncthreads();
  const int lane = threadIdx.x & 63;
  const int wid = threadIdx.x >> 6;
  const int i = blockIdx.x * 8 + wid;
  if (i >= n) return;
  const float4 adv = *(const float4*)(a_d + i * 4);
  const float4 asv = *(const float4*)(a_s + i * 4);
  float es0 = lrelu02(asv.x + adv.x);
  float es1 = lrelu02(asv.y + adv.y);
  float es2 = lrelu02(asv.z + adv.z);
  float es3 = lrelu02(asv.w + adv.w);
  const int e0 = rowp[i], e1 = rowp[i + 1];
  // pass 1: max
  float m0 = es0, m1 = es1, m2 = es2, m3 = es3;
  for (int j = e0 + lane; j < e1; j += 64) {
    int s = colsrc[j];
    const float4 av = *(const float4*)(a_s + s * 4);
    m0 = fmaxf(m0, lrelu02(av.x + adv.x));
    m1 = fmaxf(m1, lrelu02(av.y + adv.y));
    m2 = fmaxf(m2, lrelu02(av.z + adv.z));
    m3 = fmaxf(m3, lrelu02(av.w + adv.w));
  }
#pragma unroll
  for (int m = 32; m >= 1; m >>= 1) {
    m0 = fmaxf(m0, __shfl_xor(m0, m));
    m1 = fmaxf(m1, __shfl_xor(m1, m));
    m2 = fmaxf(m2, __shfl_xor(m2, m));
    m3 = fmaxf(m3, __shfl_xor(m3, m));
  }
  // pass 2: denom
  float d0 = 0.f, d1 = 0.f, d2 = 0.f, d3 = 0.f;
  for (int j = e0 + lane; j < e1; j += 64) {
    int s = colsrc[j];
    const float4 av = *(const float4*)(a_s + s * 4);
    d0 += __expf(lrelu02(av.x + adv.x) - m0);
    d1 += __expf(lrelu02(av.y + adv.y) - m1);
    d2 += __expf(lrelu02(av.z + adv.z) - m2);
    d3 += __expf(lrelu02(av.w + adv.w) - m3);
  }
#pragma unroll
  for (int m = 32; m >= 1; m >>= 1) {
    d0 += __shfl_xor(d0, m);
    d1 += __shfl_xor(d1, m);
    d2 += __shfl_xor(d2, m);
    d3 += __shfl_xor(d3, m);
  }
  d0 += __expf(es0 - m0);
  d1 += __expf(es1 - m1);
  d2 += __expf(es2 - m2);
  d3 += __expf(es3 - m3);
  const float inv0 = 1.0f / d0, inv1 = 1.0f / d1, inv2 = 1.0f / d2, inv3 = 1.0f / d3;
  const float4 asf = make_float4(__expf(es0 - m0) * inv0, __expf(es1 - m1) * inv1,
                                 __expf(es2 - m2) * inv2, __expf(es3 - m3) * inv3);
  const int col8 = lane * 8;  // elems [lane*8, lane*8+8): c0=lane*2 (h0..3), c0+1 (h0..3)
  uint4 u = *(const uint4*)(zb + (size_t)i * GATD + col8);
  float4 accC0 = make_float4(bflo(u.x) * asf.x, bfhi(u.x) * asf.y,
                             bflo(u.y) * asf.z, bfhi(u.y) * asf.w);
  float4 accC1 = make_float4(bflo(u.z) * asf.x, bfhi(u.z) * asf.y,
                             bflo(u.w) * asf.z, bfhi(u.w) * asf.w);
  // pass 3: chunked -- 64 lanes compute 64 edge-alphas, then all lanes stream messages
  for (int b = e0; b < e1; b += 64) {
    int j = b + lane;
    if (j < e1) {
      int s = colsrc[j];
      const float4 av = *(const float4*)(a_s + s * 4);
      albuf[wid][lane] = make_float4(__expf(lrelu02(av.x + adv.x) - m0) * inv0,
                                     __expf(lrelu02(av.y + adv.y) - m1) * inv1,
                                     __expf(lrelu02(av.z + adv.z) - m2) * inv2,
                                     __expf(lrelu02(av.w + adv.w) - m3) * inv3);
      sbuf[wid][lane] = s;
    }
    asm volatile("s_waitcnt lgkmcnt(0)" ::: "memory");
    const int cnt = min(64, e1 - b);
    for (int t = 0; t < cnt; ++t) {
      float4 a4 = albuf[wid][t];
      int s = sbuf[wid][t];
      uint4 w = *(const uint4*)(zb + (size_t)s * GATD + col8);
      accC0.x = fmaf(bflo(w.x), a4.x, accC0.x);
      accC0.y = fmaf(bfhi(w.x), a4.y, accC0.y);
      accC0.z = fmaf(bflo(w.y), a4.z, accC0.z);
      accC0.w = fmaf(bfhi(w.y), a4.w, accC0.w);
      accC1.x = fmaf(bflo(w.z), a4.x, accC1.x);
      accC1.y = fmaf(bfhi(w.z), a4.y, accC1.y);
      accC1.z = fmaf(bflo(w.w), a4.z, accC1.z);
      accC1.w = fmaf(bfhi(w.w), a4.w, accC1.w);
    }
  }
  const int c0 = lane * 2;
  float2 cbv = *(const float2*)(cb + c0);
  float o0 = fmaxf(accC0.x + accC0.y + accC0.z + accC0.w + cbv.x, 0.0f);
  float o1 = fmaxf(accC1.x + accC1.y + accC1.z + accC1.w + cbv.y, 0.0f);
  // fused Wout epilogue from LDS: lane owns out col `lane`; Wlds[c*64+lane] is 2-way free
  attbuf[wid][c0] = o0;
  attbuf[wid][c0 + 1] = o1;
  asm volatile("s_waitcnt lgkmcnt(0)" ::: "memory");
  float acc = bout[lane];
#pragma unroll 16
  for (int c = 0; c < HID; ++c) acc = fmaf(attbuf[wid][c], Wlds[c * 64 + lane], acc);
  outp[(size_t)i * 64 + lane] = acc;
}

extern "C" void kernel_launch(void* const* d_in, const int* in_sizes, int n_in,
                              void* d_out, int out_size, void* d_ws, size_t ws_size,
                              hipStream_t stream) {
  const float* x = (const float*)d_in[0];
  const int* ei = (const int*)d_in[1];
  const float* Win = (const float*)d_in[2];
  const float* bin = (const float*)d_in[3];
  const float* Wg1 = (const float*)d_in[4];
  const float* bg1 = (const float*)d_in[5];
  const float* g1g = (const float*)d_in[6];
  const float* g1b = (const float*)d_in[7];
  const float* Wg2 = (const float*)d_in[8];
  const float* bg2 = (const float*)d_in[9];
  const float* g2g = (const float*)d_in[10];
  const float* g2b = (const float*)d_in[11];
  const float* Wgat = (const float*)d_in[12];
  const float* att_s = (const float*)d_in[13];
  const float* att_d = (const float*)d_in[14];
  const float* bgat = (const float*)d_in[15];
  const float* Wao = (const float*)d_in[16];
  const float* bao = (const float*)d_in[17];
  const float* Wout = (const float*)d_in[18];
  const float* bout = (const float*)d_in[19];

  const int N = in_sizes[0] / 256;
  const int E = in_sizes[1] / 2;
  const int* src = ei;
  const int* dst = ei + E;

  // ---- workspace layout (bytes), ~145 MB ----
  char* base = (char*)d_ws;
  size_t off = 0;
  unsigned short* h0h = (unsigned short*)(base + off); off += (size_t)N * HID * 2;
  unsigned short* h0l = (unsigned short*)(base + off); off += (size_t)N * HID * 2;
  unsigned short* x1h = (unsigned short*)(base + off); off += (size_t)N * HID * 2;
  unsigned short* x1l = (unsigned short*)(base + off); off += (size_t)N * HID * 2;
  unsigned short* xwb = (unsigned short*)(base + off); off += (size_t)N * HID * 2;
  unsigned short* x2h = (unsigned short*)(base + off); off += (size_t)N * HID * 2;
  unsigned short* x2l = (unsigned short*)(base + off); off += (size_t)N * HID * 2;
  unsigned short* zb = (unsigned short*)(base + off); off += (size_t)N * GATD * 2;
  float* dinv = (float*)(base + off);                 off += (size_t)N * 4;
  float* a_s = (float*)(base + off);                  off += (size_t)N * 16;
  float* a_d = (float*)(base + off);                  off += (size_t)N * 16;
  float* waT = (float*)(base + off);                  off += 4096;
  float* cb = (float*)(base + off);                   off += 512;
  unsigned short *WinTh, *WinTl, *Wg1Th, *Wg1Tl, *Wg2Th, *Wg2Tl, *VTh, *VTl;
  WinTh = (unsigned short*)(base + off); off += 256 * 128 * 2;
  WinTl = (unsigned short*)(base + off); off += 256 * 128 * 2;
  Wg1Th = (unsigned short*)(base + off); off += 128 * 128 * 2;
  Wg1Tl = (unsigned short*)(base + off); off += 128 * 128 * 2;
  Wg2Th = (unsigned short*)(base + off); off += 128 * 128 * 2;
  Wg2Tl = (unsigned short*)(base + off); off += 128 * 128 * 2;
  VTh = (unsigned short*)(base + off);   off += 512 * 128 * 2;
  VTl = (unsigned short*)(base + off);   off += 512 * 128 * 2;
  int* rowp = (int*)(base + off);   off += (size_t)(N + 1) * 4;
  int* colsrc = (int*)(base + off); off += (size_t)E * 4;
  const int nb2 = (N + 1023) / 1024;
  int* bsum = (int*)(base + off);   off += (size_t)(nb2 + 2) * 4;
  int* cnt = (int*)zb;  // alias: dead before zb is written
  int* cur = cnt + N;

  const int eb = (E + TPB - 1) / TPB;
  const int zbk = (2 * N + TPB - 1) / TPB;
  const int ab = (N + 3) / 4;
  const int ab8 = (N + 7) / 8;
  const int gm = (N + 63) / 64;

  // CSR + prep
  k_zero<<<zbk, TPB, 0, stream>>>(cnt, 2 * N);
  k_hist<<<eb, TPB, 0, stream>>>(dst, cnt, E);
  k_scan_blk<<<nb2, 256, 0, stream>>>(cnt, rowp, bsum, dinv, N);
  k_scan_top<<<1, 256, 0, stream>>>(bsum, nb2);
  k_scan_add<<<(N + 255) / 256, 256, 0, stream>>>(rowp, bsum, N, nb2);
  k_fill<<<eb, TPB, 0, stream>>>(src, dst, rowp, cur, colsrc, E);
  k_prep<<<(1024 + 65536 + 128 + 255) / 256, 256, 0, stream>>>(
      Wgat, att_s, att_d, Wao, bgat, bao, waT, VTh, VTl, cb);
  k_splitw_all<<<(65536 + 255) / 256, 256, 0, stream>>>(
      Win, Wg1, Wg2, WinTh, WinTl, Wg1Th, Wg1Tl, Wg2Th, Wg2Tl);

  // h0 = relu(x @ Win + bin) -> planes    [fp32 A split in regs]
  k_gemm5<256, 64, 128, true, true, 2, 1><<<dim3(gm, 1), 256, 0, stream>>>(
      (const unsigned short*)x, nullptr, WinTh, WinTl, bin, h0h, h0l, N, 128);
  // GCN layer 1: xwb = bf16(h0 @ Wg1)
  k_gemm5<128, 64, 128, false, false, 1, 0><<<dim3(gm, 1), 256, 0, stream>>>(
      h0h, h0l, Wg1Th, Wg1Tl, nullptr, xwb, nullptr, N, 128);
  k_gcn_agg<false><<<ab, 256, 0, stream>>>(xwb, dinv, rowp, colsrc, bg1, g1g, g1b,
                                           nullptr, nullptr, x1h, x1l,
                                           nullptr, nullptr, nullptr, N);
  // GCN layer 2 (+residual, +fused GAT logits)
  k_gemm5<128, 64, 128, false, false, 1, 0><<<dim3(gm, 1), 256, 0, stream>>>(
      x1h, x1l, Wg2Th, Wg2Tl, nullptr, xwb, nullptr, N, 128);
  k_gcn_agg<true><<<ab, 256, 0, stream>>>(xwb, dinv, rowp, colsrc, bg2, g2g, g2b,
                                          x1h, x1l, x2h, x2l, waT, a_s, a_d, N);
  // z = bf16(x2 @ V)  [head-interleaved cols; NCB=256, KC=32, y=2]
  k_gemm5<128, 32, 256, false, false, 1, 0><<<dim3(gm, 2), 256, 0, stream>>>(
      x2h, x2l, VTh, VTl, nullptr, zb, nullptr, N, 512);
  // softmax-aggregate on z + LDS-staged Wout epilogue -> d_out (8 nodes/block)
  k_gat_agg3<<<ab8, 512, 0, stream>>>(zb, a_s, a_d, rowp, colsrc, cb, Wout, bout,
                                      (float*)d_out, N);
}

// Round 15
// 476.796 us; speedup vs baseline: 1.1979x; 1.0137x over previous
//
#include <hip/hip_runtime.h>
#include <hip/hip_bf16.h>
#include <cstddef>
#include <cstdint>

#define TPB 256
#define HID 128
#define GATD 512
#define HEADS 4

typedef __attribute__((ext_vector_type(8))) short bf16x8;
typedef __attribute__((ext_vector_type(4))) float f32x4;

__device__ __forceinline__ float lrelu02(float x) { return x > 0.0f ? x : 0.2f * x; }

__device__ __forceinline__ unsigned short f2bf_rn(float f) {
  uint32_t u = __float_as_uint(f);
  u += 0x7fff + ((u >> 16) & 1);
  return (unsigned short)(u >> 16);
}
__device__ __forceinline__ float bf2f(unsigned short h) {
  return __uint_as_float(((uint32_t)h) << 16);
}
__device__ __forceinline__ float bflo(uint32_t u) { return __uint_as_float(u << 16); }
__device__ __forceinline__ float bfhi(uint32_t u) { return __uint_as_float(u & 0xffff0000u); }

// ---------------- utility ----------------
__global__ void k_zero(int* __restrict__ p, int n) {
  int i = blockIdx.x * blockDim.x + threadIdx.x;
  if (i < n) p[i] = 0;
}

// ---------------- CSR build ----------------
__global__ void k_hist(const int* __restrict__ dst, int* __restrict__ cnt, int E) {
  int i = blockIdx.x * blockDim.x + threadIdx.x;
  if (i < E) atomicAdd(&cnt[dst[i]], 1);
}

__global__ __launch_bounds__(256) void k_scan_blk(const int* __restrict__ cnt,
                                                  int* __restrict__ rowp,
                                                  int* __restrict__ bsum,
                                                  float* __restrict__ dinv, int n) {
  __shared__ int wsum[4];
  const int tid = threadIdx.x, lane = tid & 63, wid = tid >> 6;
  const int base = blockIdx.x * 1024 + tid * 4;
  int v[4];
#pragma unroll
  for (int q = 0; q < 4; ++q) {
    int idx = base + q;
    v[q] = (idx < n) ? cnt[idx] : 0;
    if (idx < n) dinv[idx] = rsqrtf((float)(v[q] + 1));  // +1 self loop
  }
  int s = v[0] + v[1] + v[2] + v[3];
  int sc = s;
#pragma unroll
  for (int off = 1; off < 64; off <<= 1) {
    int t = __shfl_up(sc, off);
    if (lane >= off) sc += t;
  }
  if (lane == 63) wsum[wid] = sc;
  __syncthreads();
  int woff = 0;
#pragma unroll
  for (int w = 0; w < 4; ++w)
    if (w < wid) woff += wsum[w];
  int run = woff + sc - s;
#pragma unroll
  for (int q = 0; q < 4; ++q) {
    int idx = base + q;
    if (idx < n) rowp[idx] = run;
    run += v[q];
  }
  if (tid == 255) bsum[blockIdx.x] = woff + sc;
}

__global__ __launch_bounds__(256) void k_scan_top(int* __restrict__ bsum, int nb) {
  __shared__ int sm[256];
  const int tid = threadIdx.x;
  int v = (tid < nb) ? bsum[tid] : 0;
  sm[tid] = v;
  __syncthreads();
  for (int off = 1; off < 256; off <<= 1) {
    int t = (tid >= off) ? sm[tid - off] : 0;
    __syncthreads();
    sm[tid] += t;
    __syncthreads();
  }
  int incl = sm[tid];
  if (tid < nb) bsum[tid] = incl - v;
  if (tid == nb - 1) bsum[nb] = incl;
}

__global__ void k_scan_add(int* __restrict__ rowp, const int* __restrict__ bsum,
                           int n, int nb) {
  int i = blockIdx.x * blockDim.x + threadIdx.x;
  if (i < n) rowp[i] += bsum[i >> 10];
  if (i == 0) rowp[n] = bsum[nb];
}

__global__ void k_fill(const int* __restrict__ src, const int* __restrict__ dst,
                       const int* __restrict__ rowp, int* __restrict__ cur,
                       int* __restrict__ colsrc, int E) {
  int i = blockIdx.x * blockDim.x + threadIdx.x;
  if (i < E) {
    int d = dst[i];
    int pos = rowp[d] + atomicAdd(&cur[d], 1);
    colsrc[pos] = src[i];
  }
}

// ---------------- weight split (transposed hi/lo planes): Win, Wg1, Wg2 ----------------
__global__ void k_splitw_all(const float* __restrict__ Win, const float* __restrict__ Wg1,
                             const float* __restrict__ Wg2,
                             unsigned short* __restrict__ WinTh, unsigned short* __restrict__ WinTl,
                             unsigned short* __restrict__ Wg1Th, unsigned short* __restrict__ Wg1Tl,
                             unsigned short* __restrict__ Wg2Th, unsigned short* __restrict__ Wg2Tl) {
  int t = blockIdx.x * blockDim.x + threadIdx.x;
  const float* W;
  unsigned short *H, *L;
  int K, NC, r;
  if (t < 32768)      { W = Win; H = WinTh; L = WinTl; K = 256; NC = 128; r = t; }
  else if (t < 49152) { W = Wg1; H = Wg1Th; L = Wg1Tl; K = 128; NC = 128; r = t - 32768; }
  else if (t < 65536) { W = Wg2; H = Wg2Th; L = Wg2Tl; K = 128; NC = 128; r = t - 49152; }
  else return;
  int k = r / NC, n2 = r % NC;
  float v = W[r];
  unsigned short h = f2bf_rn(v);
  H[(size_t)n2 * K + k] = h;
  L[(size_t)n2 * K + k] = f2bf_rn(v - bf2f(h));
}

// ---------------- merged prep: waT logits-fold, V-fold planes, cbias ----------------
__global__ __launch_bounds__(256) void k_prep(const float* __restrict__ Wgat,
                                              const float* __restrict__ att_src,
                                              const float* __restrict__ att_dst,
                                              const float* __restrict__ Wao,
                                              const float* __restrict__ bgat,
                                              const float* __restrict__ bao,
                                              float* __restrict__ waT,
                                              unsigned short* __restrict__ VTh,
                                              unsigned short* __restrict__ VTl,
                                              float* __restrict__ cb) {
  int t = blockIdx.x * blockDim.x + threadIdx.x;
  if (t < 1024) {
    int p = t >> 7, k = t & 127;
    int h = p & 3;
    const float* av = (p < 4 ? att_src : att_dst) + h * HID;
    const float* wrow = Wgat + (size_t)k * GATD + h * HID;
    float s = 0.f;
#pragma unroll 4
    for (int c = 0; c < HID; ++c) s = fmaf(wrow[c], av[c], s);
    waT[t] = s;
  } else if (t < 1024 + 65536) {
    int r = t - 1024;
    int j = r >> 7, k = r & 127;
    int c = j >> 2, h = j & 3;
    const float* wg = Wgat + (size_t)k * GATD + h * HID;
    const float* wa = Wao + (size_t)(h * HID) * HID + c;
    float s = 0.f;
#pragma unroll 4
    for (int d = 0; d < HID; ++d) s = fmaf(wg[d], wa[(size_t)d * HID], s);
    unsigned short hi = f2bf_rn(s);
    VTh[(size_t)j * HID + k] = hi;
    VTl[(size_t)j * HID + k] = f2bf_rn(s - bf2f(hi));
  } else if (t < 1024 + 65536 + 128) {
    int c = t - 1024 - 65536;
    float s = bao[c];
    for (int d = 0; d < GATD; ++d) s = fmaf(bgat[d], Wao[(size_t)d * HID + c], s);
    cb[c] = s;
  }
}

// ---------------- weight-stationary MFMA GEMM, single-bf16 A, hi/lo B ----------------
// C = act(A @ W + bias); W as (BhT,BlT)[NC,KTOT] in LDS per chunk. A*B ~= A*(Bh+Bl).
// AMODE 0: A = bf16[M,KTOT].  AMODE 1: A = fp32[M,KTOT], converted in regs.
// OUTM: 0=f32 out, 1=bf16 out.
template <int KTOT, int KC, int NCB, bool RELU, bool BIAS, int OUTM, int AMODE>
__global__ __launch_bounds__(256) void k_gemm6(
    const void* __restrict__ Av,
    const unsigned short* __restrict__ BhT, const unsigned short* __restrict__ BlT,
    const float* __restrict__ bias, void* __restrict__ Cv, int M, int NC) {
  constexpr int NSUB = KC / 32;
  constexpr int NCHUNK = KTOT / KC;
  constexpr int NCF = NCB / 16;
  constexpr int UNITS = NSUB * 2 * 4 * NCB;
  __shared__ alignas(16) unsigned short Bs[NSUB][2][4][NCB][8];
  const int tid = threadIdx.x, lane = tid & 63, wid = tid >> 6;
  const int m0 = blockIdx.x * 64;
  const int n0 = blockIdx.y * NCB;
  const int fr = lane & 15, g = lane >> 4;
  const int arow = m0 + wid * 16 + fr;
  const bool aok = arow < M;
  const size_t abase = (size_t)arow * KTOT;

  f32x4 acc[NCF];
#pragma unroll
  for (int cf = 0; cf < NCF; ++cf) acc[cf] = (f32x4){0.f, 0.f, 0.f, 0.f};

  for (int c = 0; c < NCHUNK; ++c) {
    const int c0 = c * KC;
    if (c > 0) __syncthreads();
#pragma unroll
    for (int it = 0; it < UNITS / 256; ++it) {
      const int u = tid + it * 256;
      const int n = u % NCB;
      int rest = u / NCB;
      const int kg = rest & 3;
      rest >>= 2;
      const int p = rest & 1;
      const int sub = rest >> 1;
      const unsigned short* sp =
          (p ? BlT : BhT) + (size_t)(n0 + n) * KTOT + c0 + sub * 32 + kg * 8;
      *(uint4*)&Bs[sub][p][kg][n][0] = *(const uint4*)sp;
    }
    __syncthreads();
#pragma unroll
    for (int sub = 0; sub < NSUB; ++sub) {
      const int kb = c0 + sub * 32 + g * 8;
      bf16x8 a = {};
      if (aok) {
        if (AMODE == 0) {
          a = *(const bf16x8*)((const unsigned short*)Av + abase + kb);
        } else {
          const float* Af = (const float*)Av + abase + kb;
          float4 q0 = *(const float4*)Af;
          float4 q1 = *(const float4*)(Af + 4);
          float av[8] = {q0.x, q0.y, q0.z, q0.w, q1.x, q1.y, q1.z, q1.w};
          union { bf16x8 v; uint32_t u4[4]; } Hu;
#pragma unroll
          for (int q = 0; q < 4; ++q) {
            Hu.u4[q] = (uint32_t)f2bf_rn(av[2 * q]) | ((uint32_t)f2bf_rn(av[2 * q + 1]) << 16);
          }
          a = Hu.v;
        }
      }
#pragma unroll
      for (int cf = 0; cf < NCF; ++cf) {
        bf16x8 b_h = *(const bf16x8*)&Bs[sub][0][g][cf * 16 + fr][0];
        bf16x8 b_l = *(const bf16x8*)&Bs[sub][1][g][cf * 16 + fr][0];
        acc[cf] = __builtin_amdgcn_mfma_f32_16x16x32_bf16(a, b_h, acc[cf], 0, 0, 0);
        acc[cf] = __builtin_amdgcn_mfma_f32_16x16x32_bf16(a, b_l, acc[cf], 0, 0, 0);
      }
    }
  }
#pragma unroll
  for (int cf = 0; cf < NCF; ++cf) {
    const int col = n0 + cf * 16 + fr;
    const float bv = BIAS ? bias[col] : 0.f;
#pragma unroll
    for (int r = 0; r < 4; ++r) {
      const int grow = m0 + wid * 16 + g * 4 + r;
      if (grow < M) {
        float v = acc[cf][r] + bv;
        if (RELU) v = fmaxf(v, 0.f);
        const size_t idx = (size_t)grow * NC + col;
        if (OUTM == 0) ((float*)Cv)[idx] = v;
        else ((unsigned short*)Cv)[idx] = f2bf_rn(v);
      }
    }
  }
}

// ---------------- GCN aggregate (bf16 gather) + bias + LN + ReLU (+residual, +GAT logits) ----------------
template <bool L2>
__global__ __launch_bounds__(256) void k_gcn_agg(
    const unsigned short* __restrict__ xwb, const float* __restrict__ dinv,
    const int* __restrict__ rowp, const int* __restrict__ colsrc,
    const float* __restrict__ bias, const float* __restrict__ gamma,
    const float* __restrict__ beta,
    const unsigned short* __restrict__ resb,
    unsigned short* __restrict__ ob,
    const float* __restrict__ waT, float* __restrict__ a_s, float* __restrict__ a_d,
    int n) {
  __shared__ float w[8][HID];
  if (L2) {
    for (int t = threadIdx.x; t < 8 * HID; t += 256) ((float*)w)[t] = waT[t];
    __syncthreads();
  }
  const int lane = threadIdx.x & 63;
  const int i = blockIdx.x * 4 + (threadIdx.x >> 6);
  if (i >= n) return;
  const float di = dinv[i];
  const int c = lane * 2;
  uint32_t v0 = *(const uint32_t*)(xwb + (size_t)i * HID + c);
  float a0 = bflo(v0) * di * di, a1 = bfhi(v0) * di * di;  // self loop
  float b0 = 0.f, b1 = 0.f;
  const int e0 = rowp[i], e1 = rowp[i + 1];
  int j = e0;
  for (; j + 7 < e1; j += 8) {
    int ss[8];
    float ww[8];
    uint32_t uu[8];
#pragma unroll
    for (int q = 0; q < 8; ++q) ss[q] = colsrc[j + q];
#pragma unroll
    for (int q = 0; q < 8; ++q) ww[q] = dinv[ss[q]] * di;
#pragma unroll
    for (int q = 0; q < 8; ++q) uu[q] = *(const uint32_t*)(xwb + (size_t)ss[q] * HID + c);
#pragma unroll
    for (int q = 0; q < 8; ++q) {
      if (q & 1) {
        b0 = fmaf(bflo(uu[q]), ww[q], b0);
        b1 = fmaf(bfhi(uu[q]), ww[q], b1);
      } else {
        a0 = fmaf(bflo(uu[q]), ww[q], a0);
        a1 = fmaf(bfhi(uu[q]), ww[q], a1);
      }
    }
  }
  for (; j < e1; ++j) {
    int s0 = colsrc[j];
    float w0 = dinv[s0] * di;
    uint32_t u0 = *(const uint32_t*)(xwb + (size_t)s0 * HID + c);
    a0 = fmaf(bflo(u0), w0, a0);
    a1 = fmaf(bfhi(u0), w0, a1);
  }
  a0 += b0;
  a1 += b1;
  a0 += bias[c];
  a1 += bias[c + 1];
  float s1 = a0 + a1, s2 = a0 * a0 + a1 * a1;
#pragma unroll
  for (int m = 32; m >= 1; m >>= 1) {
    s1 += __shfl_xor(s1, m);
    s2 += __shfl_xor(s2, m);
  }
  float mu = s1 * (1.0f / HID);
  float var = s2 * (1.0f / HID) - mu * mu;
  float rstd = rsqrtf(var + 1e-5f);
  float y0 = fmaxf((a0 - mu) * rstd * gamma[c] + beta[c], 0.0f);
  float y1 = fmaxf((a1 - mu) * rstd * gamma[c + 1] + beta[c + 1], 0.0f);
  if (L2) {
    uint32_t rb = *(const uint32_t*)(resb + (size_t)i * HID + c);
    y0 += bflo(rb);
    y1 += bfhi(rb);
  }
  *(uint32_t*)(ob + (size_t)i * HID + c) =
      (uint32_t)f2bf_rn(y0) | ((uint32_t)f2bf_rn(y1) << 16);
  if (L2) {
    float p[8];
#pragma unroll
    for (int h = 0; h < 8; ++h) p[h] = y0 * w[h][c] + y1 * w[h][c + 1];
#pragma unroll
    for (int m = 32; m >= 1; m >>= 1) {
#pragma unroll
      for (int h = 0; h < 8; ++h) p[h] += __shfl_xor(p[h], m);
    }
    if (lane == 0) {
      a_s[i * 4 + 0] = p[0]; a_s[i * 4 + 1] = p[1];
      a_s[i * 4 + 2] = p[2]; a_s[i * 4 + 3] = p[3];
      a_d[i * 4 + 0] = p[4]; a_d[i * 4 + 1] = p[5];
      a_d[i * 4 + 2] = p[6]; a_d[i * 4 + 3] = p[7];
    }
  }
}

// ---------------- GAT softmax-aggregate on folded z + LDS-staged Wout epilogue -> d_out ----------------
// 512-thread blocks: 8 waves = 8 nodes/block, Wout LDS copy amortized, ~24 waves/CU.
__global__ __launch_bounds__(512) void k_gat_agg3(const unsigned short* __restrict__ zb,
                                                  const float* __restrict__ a_s,
                                                  const float* __restrict__ a_d,
                                                  const int* __restrict__ rowp,
                                                  const int* __restrict__ colsrc,
                                                  const float* __restrict__ cb,
                                                  const float* __restrict__ Wout,
                                                  const float* __restrict__ bout,
                                                  float* __restrict__ outp,
                                                  int n) {
  __shared__ float4 albuf[8][64];
  __shared__ int sbuf[8][64];
  __shared__ float attbuf[8][HID];
  __shared__ float Wlds[HID * 64];  // Wout natural layout [c][cp], 32 KB
  for (int t = threadIdx.x; t < HID * 64 / 4; t += 512)
    *(float4*)&Wlds[t * 4] = *(const float4*)&Wout[t * 4];
  __syncthreads();
  const int lane = threadIdx.x & 63;
  const int wid = threadIdx.x >> 6;
  const int i = blockIdx.x * 8 + wid;
  if (i >= n) return;
  const float4 adv = *(const float4*)(a_d + i * 4);
  const float4 asv = *(const float4*)(a_s + i * 4);
  float es0 = lrelu02(asv.x + adv.x);
  float es1 = lrelu02(asv.y + adv.y);
  float es2 = lrelu02(asv.z + adv.z);
  float es3 = lrelu02(asv.w + adv.w);
  const int e0 = rowp[i], e1 = rowp[i + 1];
  float m0 = es0, m1 = es1, m2 = es2, m3 = es3;
  for (int j = e0 + lane; j < e1; j += 64) {
    int s = colsrc[j];
    const float4 av = *(const float4*)(a_s + s * 4);
    m0 = fmaxf(m0, lrelu02(av.x + adv.x));
    m1 = fmaxf(m1, lrelu02(av.y + adv.y));
    m2 = fmaxf(m2, lrelu02(av.z + adv.z));
    m3 = fmaxf(m3, lrelu02(av.w + adv.w));
  }
#pragma unroll
  for (int m = 32; m >= 1; m >>= 1) {
    m0 = fmaxf(m0, __shfl_xor(m0, m));
    m1 = fmaxf(m1, __shfl_xor(m1, m));
    m2 = fmaxf(m2, __shfl_xor(m2, m));
    m3 = fmaxf(m3, __shfl_xor(m3, m));
  }
  float d0 = 0.f, d1 = 0.f, d2 = 0.f, d3 = 0.f;
  for (int j = e0 + lane; j < e1; j += 64) {
    int s = colsrc[j];
    const float4 av = *(const float4*)(a_s + s * 4);
    d0 += __expf(lrelu02(av.x + adv.x) - m0);
    d1 += __expf(lrelu02(av.y + adv.y) - m1);
    d2 += __expf(lrelu02(av.z + adv.z) - m2);
    d3 += __expf(lrelu02(av.w + adv.w) - m3);
  }
#pragma unroll
  for (int m = 32; m >= 1; m >>= 1) {
    d0 += __shfl_xor(d0, m);
    d1 += __shfl_xor(d1, m);
    d2 += __shfl_xor(d2, m);
    d3 += __shfl_xor(d3, m);
  }
  d0 += __expf(es0 - m0);
  d1 += __expf(es1 - m1);
  d2 += __expf(es2 - m2);
  d3 += __expf(es3 - m3);
  const float inv0 = 1.0f / d0, inv1 = 1.0f / d1, inv2 = 1.0f / d2, inv3 = 1.0f / d3;
  const float4 asf = make_float4(__expf(es0 - m0) * inv0, __expf(es1 - m1) * inv1,
                                 __expf(es2 - m2) * inv2, __expf(es3 - m3) * inv3);
  const int col8 = lane * 8;
  uint4 u = *(const uint4*)(zb + (size_t)i * GATD + col8);
  float4 accC0 = make_float4(bflo(u.x) * asf.x, bfhi(u.x) * asf.y,
                             bflo(u.y) * asf.z, bfhi(u.y) * asf.w);
  float4 accC1 = make_float4(bflo(u.z) * asf.x, bfhi(u.z) * asf.y,
                             bflo(u.w) * asf.z, bfhi(u.w) * asf.w);
  for (int b = e0; b < e1; b += 64) {
    int j = b + lane;
    if (j < e1) {
      int s = colsrc[j];
      const float4 av = *(const float4*)(a_s + s * 4);
      albuf[wid][lane] = make_float4(__expf(lrelu02(av.x + adv.x) - m0) * inv0,
                                     __expf(lrelu02(av.y + adv.y) - m1) * inv1,
                                     __expf(lrelu02(av.z + adv.z) - m2) * inv2,
                                     __expf(lrelu02(av.w + adv.w) - m3) * inv3);
      sbuf[wid][lane] = s;
    }
    asm volatile("s_waitcnt lgkmcnt(0)" ::: "memory");
    const int cnt = min(64, e1 - b);
    for (int t = 0; t < cnt; ++t) {
      float4 a4 = albuf[wid][t];
      int s = sbuf[wid][t];
      uint4 w = *(const uint4*)(zb + (size_t)s * GATD + col8);
      accC0.x = fmaf(bflo(w.x), a4.x, accC0.x);
      accC0.y = fmaf(bfhi(w.x), a4.y, accC0.y);
      accC0.z = fmaf(bflo(w.y), a4.z, accC0.z);
      accC0.w = fmaf(bfhi(w.y), a4.w, accC0.w);
      accC1.x = fmaf(bflo(w.z), a4.x, accC1.x);
      accC1.y = fmaf(bfhi(w.z), a4.y, accC1.y);
      accC1.z = fmaf(bflo(w.w), a4.z, accC1.z);
      accC1.w = fmaf(bfhi(w.w), a4.w, accC1.w);
    }
  }
  const int c0 = lane * 2;
  float2 cbv = *(const float2*)(cb + c0);
  float o0 = fmaxf(accC0.x + accC0.y + accC0.z + accC0.w + cbv.x, 0.0f);
  float o1 = fmaxf(accC1.x + accC1.y + accC1.z + accC1.w + cbv.y, 0.0f);
  attbuf[wid][c0] = o0;
  attbuf[wid][c0 + 1] = o1;
  asm volatile("s_waitcnt lgkmcnt(0)" ::: "memory");
  float acc = bout[lane];
#pragma unroll 16
  for (int c = 0; c < HID; ++c) acc = fmaf(attbuf[wid][c], Wlds[c * 64 + lane], acc);
  outp[(size_t)i * 64 + lane] = acc;
}

extern "C" void kernel_launch(void* const* d_in, const int* in_sizes, int n_in,
                              void* d_out, int out_size, void* d_ws, size_t ws_size,
                              hipStream_t stream) {
  const float* x = (const float*)d_in[0];
  const int* ei = (const int*)d_in[1];
  const float* Win = (const float*)d_in[2];
  const float* bin = (const float*)d_in[3];
  const float* Wg1 = (const float*)d_in[4];
  const float* bg1 = (const float*)d_in[5];
  const float* g1g = (const float*)d_in[6];
  const float* g1b = (const float*)d_in[7];
  const float* Wg2 = (const float*)d_in[8];
  const float* bg2 = (const float*)d_in[9];
  const float* g2g = (const float*)d_in[10];
  const float* g2b = (const float*)d_in[11];
  const float* Wgat = (const float*)d_in[12];
  const float* att_s = (const float*)d_in[13];
  const float* att_d = (const float*)d_in[14];
  const float* bgat = (const float*)d_in[15];
  const float* Wao = (const float*)d_in[16];
  const float* bao = (const float*)d_in[17];
  const float* Wout = (const float*)d_in[18];
  const float* bout = (const float*)d_in[19];

  const int N = in_sizes[0] / 256;
  const int E = in_sizes[1] / 2;
  const int* src = ei;
  const int* dst = ei + E;

  // ---- workspace layout (bytes), ~120 MB ----
  char* base = (char*)d_ws;
  size_t off = 0;
  unsigned short* h0b = (unsigned short*)(base + off); off += (size_t)N * HID * 2;
  unsigned short* x1b = (unsigned short*)(base + off); off += (size_t)N * HID * 2;
  unsigned short* xwb = (unsigned short*)(base + off); off += (size_t)N * HID * 2;
  unsigned short* x2b = (unsigned short*)(base + off); off += (size_t)N * HID * 2;
  unsigned short* zb = (unsigned short*)(base + off); off += (size_t)N * GATD * 2;
  float* dinv = (float*)(base + off);                 off += (size_t)N * 4;
  float* a_s = (float*)(base + off);                  off += (size_t)N * 16;
  float* a_d = (float*)(base + off);                  off += (size_t)N * 16;
  float* waT = (float*)(base + off);                  off += 4096;
  float* cb = (float*)(base + off);                   off += 512;
  unsigned short *WinTh, *WinTl, *Wg1Th, *Wg1Tl, *Wg2Th, *Wg2Tl, *VTh, *VTl;
  WinTh = (unsigned short*)(base + off); off += 256 * 128 * 2;
  WinTl = (unsigned short*)(base + off); off += 256 * 128 * 2;
  Wg1Th = (unsigned short*)(base + off); off += 128 * 128 * 2;
  Wg1Tl = (unsigned short*)(base + off); off += 128 * 128 * 2;
  Wg2Th = (unsigned short*)(base + off); off += 128 * 128 * 2;
  Wg2Tl = (unsigned short*)(base + off); off += 128 * 128 * 2;
  VTh = (unsigned short*)(base + off);   off += 512 * 128 * 2;
  VTl = (unsigned short*)(base + off);   off += 512 * 128 * 2;
  int* rowp = (int*)(base + off);   off += (size_t)(N + 1) * 4;
  int* colsrc = (int*)(base + off); off += (size_t)E * 4;
  const int nb2 = (N + 1023) / 1024;
  int* bsum = (int*)(base + off);   off += (size_t)(nb2 + 2) * 4;
  int* cnt = (int*)zb;  // alias: dead before zb is written
  int* cur = cnt + N;

  const int eb = (E + TPB - 1) / TPB;
  const int zbk = (2 * N + TPB - 1) / TPB;
  const int ab = (N + 3) / 4;
  const int ab8 = (N + 7) / 8;
  const int gm = (N + 63) / 64;

  // CSR + prep
  k_zero<<<zbk, TPB, 0, stream>>>(cnt, 2 * N);
  k_hist<<<eb, TPB, 0, stream>>>(dst, cnt, E);
  k_scan_blk<<<nb2, 256, 0, stream>>>(cnt, rowp, bsum, dinv, N);
  k_scan_top<<<1, 256, 0, stream>>>(bsum, nb2);
  k_scan_add<<<(N + 255) / 256, 256, 0, stream>>>(rowp, bsum, N, nb2);
  k_fill<<<eb, TPB, 0, stream>>>(src, dst, rowp, cur, colsrc, E);
  k_prep<<<(1024 + 65536 + 128 + 255) / 256, 256, 0, stream>>>(
      Wgat, att_s, att_d, Wao, bgat, bao, waT, VTh, VTl, cb);
  k_splitw_all<<<(65536 + 255) / 256, 256, 0, stream>>>(
      Win, Wg1, Wg2, WinTh, WinTl, Wg1Th, Wg1Tl, Wg2Th, Wg2Tl);

  // h0 = relu(x @ Win + bin) -> bf16     [fp32 A converted in regs]
  k_gemm6<256, 64, 128, true, true, 1, 1><<<dim3(gm, 1), 256, 0, stream>>>(
      x, WinTh, WinTl, bin, h0b, N, 128);
  // GCN layer 1: xwb = bf16(h0 @ Wg1)
  k_gemm6<128, 64, 128, false, false, 1, 0><<<dim3(gm, 1), 256, 0, stream>>>(
      h0b, Wg1Th, Wg1Tl, nullptr, xwb, N, 128);
  k_gcn_agg<false><<<ab, 256, 0, stream>>>(xwb, dinv, rowp, colsrc, bg1, g1g, g1b,
                                           nullptr, x1b, nullptr, nullptr, nullptr, N);
  // GCN layer 2 (+residual, +fused GAT logits)
  k_gemm6<128, 64, 128, false, false, 1, 0><<<dim3(gm, 1), 256, 0, stream>>>(
      x1b, Wg2Th, Wg2Tl, nullptr, xwb, N, 128);
  k_gcn_agg<true><<<ab, 256, 0, stream>>>(xwb, dinv, rowp, colsrc, bg2, g2g, g2b,
                                          x1b, x2b, waT, a_s, a_d, N);
  // z = bf16(x2 @ V)  [head-interleaved cols; NCB=256, KC=32, y=2]
  k_gemm6<128, 32, 256, false, false, 1, 0><<<dim3(gm, 2), 256, 0, stream>>>(
      x2b, VTh, VTl, nullptr, zb, N, 512);
  // softmax-aggregate on z + LDS-staged Wout epilogue -> d_out (8 nodes/block)
  k_gat_agg3<<<ab8, 512, 0, stream>>>(zb, a_s, a_d, rowp, colsrc, cb, Wout, bout,
                                      (float*)d_out, N);
}

// Round 16
// 419.110 us; speedup vs baseline: 1.3627x; 1.1376x over previous
//
#include <hip/hip_runtime.h>
#include <hip/hip_bf16.h>
#include <cstddef>
#include <cstdint>

#define TPB 256
#define HID 128
#define GATD 512
#define HEADS 4

typedef __attribute__((ext_vector_type(8))) short bf16x8;
typedef __attribute__((ext_vector_type(4))) float f32x4;

__device__ __forceinline__ float lrelu02(float x) { return x > 0.0f ? x : 0.2f * x; }

__device__ __forceinline__ unsigned short f2bf_rn(float f) {
  uint32_t u = __float_as_uint(f);
  u += 0x7fff + ((u >> 16) & 1);
  return (unsigned short)(u >> 16);
}
__device__ __forceinline__ float bf2f(unsigned short h) {
  return __uint_as_float(((uint32_t)h) << 16);
}
__device__ __forceinline__ float bflo(uint32_t u) { return __uint_as_float(u << 16); }
__device__ __forceinline__ float bfhi(uint32_t u) { return __uint_as_float(u & 0xffff0000u); }

// ---------------- utility ----------------
__global__ void k_zero(int* __restrict__ p, int n) {
  int i = blockIdx.x * blockDim.x + threadIdx.x;
  if (i < n) p[i] = 0;
}

// ---------------- CSR build ----------------
__global__ void k_hist(const int* __restrict__ dst, int* __restrict__ cnt, int E) {
  int i = blockIdx.x * blockDim.x + threadIdx.x;
  if (i < E) atomicAdd(&cnt[dst[i]], 1);
}

__global__ __launch_bounds__(256) void k_scan_blk(const int* __restrict__ cnt,
                                                  int* __restrict__ rowp,
                                                  int* __restrict__ bsum,
                                                  float* __restrict__ dinv, int n) {
  __shared__ int wsum[4];
  const int tid = threadIdx.x, lane = tid & 63, wid = tid >> 6;
  const int base = blockIdx.x * 1024 + tid * 4;
  int v[4];
#pragma unroll
  for (int q = 0; q < 4; ++q) {
    int idx = base + q;
    v[q] = (idx < n) ? cnt[idx] : 0;
    if (idx < n) dinv[idx] = rsqrtf((float)(v[q] + 1));  // +1 self loop
  }
  int s = v[0] + v[1] + v[2] + v[3];
  int sc = s;
#pragma unroll
  for (int off = 1; off < 64; off <<= 1) {
    int t = __shfl_up(sc, off);
    if (lane >= off) sc += t;
  }
  if (lane == 63) wsum[wid] = sc;
  __syncthreads();
  int woff = 0;
#pragma unroll
  for (int w = 0; w < 4; ++w)
    if (w < wid) woff += wsum[w];
  int run = woff + sc - s;
#pragma unroll
  for (int q = 0; q < 4; ++q) {
    int idx = base + q;
    if (idx < n) rowp[idx] = run;
    run += v[q];
  }
  if (tid == 255) bsum[blockIdx.x] = woff + sc;
}

__global__ __launch_bounds__(256) void k_scan_top(int* __restrict__ bsum, int nb) {
  __shared__ int sm[256];
  const int tid = threadIdx.x;
  int v = (tid < nb) ? bsum[tid] : 0;
  sm[tid] = v;
  __syncthreads();
  for (int off = 1; off < 256; off <<= 1) {
    int t = (tid >= off) ? sm[tid - off] : 0;
    __syncthreads();
    sm[tid] += t;
    __syncthreads();
  }
  int incl = sm[tid];
  if (tid < nb) bsum[tid] = incl - v;
  if (tid == nb - 1) bsum[nb] = incl;
}

__global__ void k_scan_add(int* __restrict__ rowp, const int* __restrict__ bsum,
                           int n, int nb) {
  int i = blockIdx.x * blockDim.x + threadIdx.x;
  if (i < n) rowp[i] += bsum[i >> 10];
  if (i == 0) rowp[n] = bsum[nb];
}

__global__ void k_fill(const int* __restrict__ src, const int* __restrict__ dst,
                       const int* __restrict__ rowp, int* __restrict__ cur,
                       int* __restrict__ colsrc, int E) {
  int i = blockIdx.x * blockDim.x + threadIdx.x;
  if (i < E) {
    int d = dst[i];
    int pos = rowp[d] + atomicAdd(&cur[d], 1);
    colsrc[pos] = src[i];
  }
}

// ---------------- weight split (transposed hi/lo planes): Win, Wg1, Wg2, Wout ----------------
__global__ void k_splitw_all(const float* __restrict__ Win, const float* __restrict__ Wg1,
                             const float* __restrict__ Wg2, const float* __restrict__ Wout,
                             unsigned short* __restrict__ WinTh, unsigned short* __restrict__ WinTl,
                             unsigned short* __restrict__ Wg1Th, unsigned short* __restrict__ Wg1Tl,
                             unsigned short* __restrict__ Wg2Th, unsigned short* __restrict__ Wg2Tl,
                             unsigned short* __restrict__ WoutTh, unsigned short* __restrict__ WoutTl) {
  int t = blockIdx.x * blockDim.x + threadIdx.x;
  const float* W;
  unsigned short *H, *L;
  int K, NC, r;
  if (t < 32768)      { W = Win;  H = WinTh;  L = WinTl;  K = 256; NC = 128; r = t; }
  else if (t < 49152) { W = Wg1;  H = Wg1Th;  L = Wg1Tl;  K = 128; NC = 128; r = t - 32768; }
  else if (t < 65536) { W = Wg2;  H = Wg2Th;  L = Wg2Tl;  K = 128; NC = 128; r = t - 49152; }
  else if (t < 73728) { W = Wout; H = WoutTh; L = WoutTl; K = 128; NC = 64;  r = t - 65536; }
  else return;
  int k = r / NC, n2 = r % NC;
  float v = W[r];
  unsigned short h = f2bf_rn(v);
  H[(size_t)n2 * K + k] = h;
  L[(size_t)n2 * K + k] = f2bf_rn(v - bf2f(h));
}

// ---------------- merged prep: waT logits-fold, V2 planes (u-GEMM B), cbias ----------------
// V2T[c][k*4+h] = V_h[k][c] where V_h = Wgat_h @ Wao_h  (rows c: KTOT=512, j interleaved k*4+h)
__global__ __launch_bounds__(256) void k_prep(const float* __restrict__ Wgat,
                                              const float* __restrict__ att_src,
                                              const float* __restrict__ att_dst,
                                              const float* __restrict__ Wao,
                                              const float* __restrict__ bgat,
                                              const float* __restrict__ bao,
                                              float* __restrict__ waT,
                                              unsigned short* __restrict__ V2Th,
                                              unsigned short* __restrict__ V2Tl,
                                              float* __restrict__ cb) {
  int t = blockIdx.x * blockDim.x + threadIdx.x;
  if (t < 1024) {
    int p = t >> 7, k = t & 127;
    int h = p & 3;
    const float* av = (p < 4 ? att_src : att_dst) + h * HID;
    const float* wrow = Wgat + (size_t)k * GATD + h * HID;
    float s = 0.f;
#pragma unroll 4
    for (int c = 0; c < HID; ++c) s = fmaf(wrow[c], av[c], s);
    waT[t] = s;
  } else if (t < 1024 + 65536) {
    int r = t - 1024;
    int j = r >> 7, k = r & 127;
    int c = j >> 2, h = j & 3;
    const float* wg = Wgat + (size_t)k * GATD + h * HID;
    const float* wa = Wao + (size_t)(h * HID) * HID + c;
    float s = 0.f;
#pragma unroll 4
    for (int d = 0; d < HID; ++d) s = fmaf(wg[d], wa[(size_t)d * HID], s);
    unsigned short hi = f2bf_rn(s);
    V2Th[(size_t)c * GATD + k * 4 + h] = hi;
    V2Tl[(size_t)c * GATD + k * 4 + h] = f2bf_rn(s - bf2f(hi));
  } else if (t < 1024 + 65536 + 128) {
    int c = t - 1024 - 65536;
    float s = bao[c];
    for (int d = 0; d < GATD; ++d) s = fmaf(bgat[d], Wao[(size_t)d * HID + c], s);
    cb[c] = s;
  }
}

// ---------------- weight-stationary MFMA GEMM, single-bf16 A, hi/lo B ----------------
// C = act(A @ W + bias); W as (BhT,BlT)[NC,KTOT] in LDS per chunk. A*B ~= A*(Bh+Bl).
// AMODE 0: A = bf16[M,KTOT].  AMODE 1: A = fp32[M,KTOT], converted in regs.
// OUTM: 0=f32 out, 1=bf16 out.
template <int KTOT, int KC, int NCB, bool RELU, bool BIAS, int OUTM, int AMODE>
__global__ __launch_bounds__(256) void k_gemm6(
    const void* __restrict__ Av,
    const unsigned short* __restrict__ BhT, const unsigned short* __restrict__ BlT,
    const float* __restrict__ bias, void* __restrict__ Cv, int M, int NC) {
  constexpr int NSUB = KC / 32;
  constexpr int NCHUNK = KTOT / KC;
  constexpr int NCF = NCB / 16;
  constexpr int UNITS = NSUB * 2 * 4 * NCB;
  __shared__ alignas(16) unsigned short Bs[NSUB][2][4][NCB][8];
  const int tid = threadIdx.x, lane = tid & 63, wid = tid >> 6;
  const int m0 = blockIdx.x * 64;
  const int n0 = blockIdx.y * NCB;
  const int fr = lane & 15, g = lane >> 4;
  const int arow = m0 + wid * 16 + fr;
  const bool aok = arow < M;
  const size_t abase = (size_t)arow * KTOT;

  f32x4 acc[NCF];
#pragma unroll
  for (int cf = 0; cf < NCF; ++cf) acc[cf] = (f32x4){0.f, 0.f, 0.f, 0.f};

  for (int c = 0; c < NCHUNK; ++c) {
    const int c0 = c * KC;
    if (c > 0) __syncthreads();
#pragma unroll
    for (int it = 0; it < UNITS / 256; ++it) {
      const int u = tid + it * 256;
      const int n = u % NCB;
      int rest = u / NCB;
      const int kg = rest & 3;
      rest >>= 2;
      const int p = rest & 1;
      const int sub = rest >> 1;
      const unsigned short* sp =
          (p ? BlT : BhT) + (size_t)(n0 + n) * KTOT + c0 + sub * 32 + kg * 8;
      *(uint4*)&Bs[sub][p][kg][n][0] = *(const uint4*)sp;
    }
    __syncthreads();
#pragma unroll
    for (int sub = 0; sub < NSUB; ++sub) {
      const int kb = c0 + sub * 32 + g * 8;
      bf16x8 a = {};
      if (aok) {
        if (AMODE == 0) {
          a = *(const bf16x8*)((const unsigned short*)Av + abase + kb);
        } else {
          const float* Af = (const float*)Av + abase + kb;
          float4 q0 = *(const float4*)Af;
          float4 q1 = *(const float4*)(Af + 4);
          float av[8] = {q0.x, q0.y, q0.z, q0.w, q1.x, q1.y, q1.z, q1.w};
          union { bf16x8 v; uint32_t u4[4]; } Hu;
#pragma unroll
          for (int q = 0; q < 4; ++q) {
            Hu.u4[q] = (uint32_t)f2bf_rn(av[2 * q]) | ((uint32_t)f2bf_rn(av[2 * q + 1]) << 16);
          }
          a = Hu.v;
        }
      }
#pragma unroll
      for (int cf = 0; cf < NCF; ++cf) {
        bf16x8 b_h = *(const bf16x8*)&Bs[sub][0][g][cf * 16 + fr][0];
        bf16x8 b_l = *(const bf16x8*)&Bs[sub][1][g][cf * 16 + fr][0];
        acc[cf] = __builtin_amdgcn_mfma_f32_16x16x32_bf16(a, b_h, acc[cf], 0, 0, 0);
        acc[cf] = __builtin_amdgcn_mfma_f32_16x16x32_bf16(a, b_l, acc[cf], 0, 0, 0);
      }
    }
  }
#pragma unroll
  for (int cf = 0; cf < NCF; ++cf) {
    const int col = n0 + cf * 16 + fr;
    const float bv = BIAS ? bias[col] : 0.f;
#pragma unroll
    for (int r = 0; r < 4; ++r) {
      const int grow = m0 + wid * 16 + g * 4 + r;
      if (grow < M) {
        float v = acc[cf][r] + bv;
        if (RELU) v = fmaxf(v, 0.f);
        const size_t idx = (size_t)grow * NC + col;
        if (OUTM == 0) ((float*)Cv)[idx] = v;
        else ((unsigned short*)Cv)[idx] = f2bf_rn(v);
      }
    }
  }
}

// ---------------- GCN aggregate (bf16 gather) + bias + LN + ReLU (+residual, +GAT logits) ----------------
template <bool L2>
__global__ __launch_bounds__(256) void k_gcn_agg(
    const unsigned short* __restrict__ xwb, const float* __restrict__ dinv,
    const int* __restrict__ rowp, const int* __restrict__ colsrc,
    const float* __restrict__ bias, const float* __restrict__ gamma,
    const float* __restrict__ beta,
    const unsigned short* __restrict__ resb,
    unsigned short* __restrict__ ob,
    const float* __restrict__ waT, float* __restrict__ a_s, float* __restrict__ a_d,
    int n) {
  __shared__ float w[8][HID];
  if (L2) {
    for (int t = threadIdx.x; t < 8 * HID; t += 256) ((float*)w)[t] = waT[t];
    __syncthreads();
  }
  const int lane = threadIdx.x & 63;
  const int i = blockIdx.x * 4 + (threadIdx.x >> 6);
  if (i >= n) return;
  const float di = dinv[i];
  const int c = lane * 2;
  uint32_t v0 = *(const uint32_t*)(xwb + (size_t)i * HID + c);
  float a0 = bflo(v0) * di * di, a1 = bfhi(v0) * di * di;  // self loop
  float b0 = 0.f, b1 = 0.f;
  const int e0 = rowp[i], e1 = rowp[i + 1];
  int j = e0;
  for (; j + 7 < e1; j += 8) {
    int ss[8];
    float ww[8];
    uint32_t uu[8];
#pragma unroll
    for (int q = 0; q < 8; ++q) ss[q] = colsrc[j + q];
#pragma unroll
    for (int q = 0; q < 8; ++q) ww[q] = dinv[ss[q]] * di;
#pragma unroll
    for (int q = 0; q < 8; ++q) uu[q] = *(const uint32_t*)(xwb + (size_t)ss[q] * HID + c);
#pragma unroll
    for (int q = 0; q < 8; ++q) {
      if (q & 1) {
        b0 = fmaf(bflo(uu[q]), ww[q], b0);
        b1 = fmaf(bfhi(uu[q]), ww[q], b1);
      } else {
        a0 = fmaf(bflo(uu[q]), ww[q], a0);
        a1 = fmaf(bfhi(uu[q]), ww[q], a1);
      }
    }
  }
  for (; j < e1; ++j) {
    int s0 = colsrc[j];
    float w0 = dinv[s0] * di;
    uint32_t u0 = *(const uint32_t*)(xwb + (size_t)s0 * HID + c);
    a0 = fmaf(bflo(u0), w0, a0);
    a1 = fmaf(bfhi(u0), w0, a1);
  }
  a0 += b0;
  a1 += b1;
  a0 += bias[c];
  a1 += bias[c + 1];
  float s1 = a0 + a1, s2 = a0 * a0 + a1 * a1;
#pragma unroll
  for (int m = 32; m >= 1; m >>= 1) {
    s1 += __shfl_xor(s1, m);
    s2 += __shfl_xor(s2, m);
  }
  float mu = s1 * (1.0f / HID);
  float var = s2 * (1.0f / HID) - mu * mu;
  float rstd = rsqrtf(var + 1e-5f);
  float y0 = fmaxf((a0 - mu) * rstd * gamma[c] + beta[c], 0.0f);
  float y1 = fmaxf((a1 - mu) * rstd * gamma[c + 1] + beta[c + 1], 0.0f);
  if (L2) {
    uint32_t rb = *(const uint32_t*)(resb + (size_t)i * HID + c);
    y0 += bflo(rb);
    y1 += bfhi(rb);
  }
  *(uint32_t*)(ob + (size_t)i * HID + c) =
      (uint32_t)f2bf_rn(y0) | ((uint32_t)f2bf_rn(y1) << 16);
  if (L2) {
    float p[8];
#pragma unroll
    for (int h = 0; h < 8; ++h) p[h] = y0 * w[h][c] + y1 * w[h][c + 1];
#pragma unroll
    for (int m = 32; m >= 1; m >>= 1) {
#pragma unroll
      for (int h = 0; h < 8; ++h) p[h] += __shfl_xor(p[h], m);
    }
    if (lane == 0) {
      a_s[i * 4 + 0] = p[0]; a_s[i * 4 + 1] = p[1];
      a_s[i * 4 + 2] = p[2]; a_s[i * 4 + 3] = p[3];
      a_d[i * 4 + 0] = p[4]; a_d[i * 4 + 1] = p[5];
      a_d[i * 4 + 2] = p[6]; a_d[i * 4 + 3] = p[7];
    }
  }
}

// ---------------- GAT softmax-aggregate on x2 (4x less gather): u_h[i] = sum_s alpha_h x2[s] ----------------
// Output u[N][512] bf16, j = k*4+h head-interleaved. Wave per node; lane owns cols 2.
__global__ __launch_bounds__(256) void k_gat_agg4(const unsigned short* __restrict__ x2b,
                                                  const float* __restrict__ a_s,
                                                  const float* __restrict__ a_d,
                                                  const int* __restrict__ rowp,
                                                  const int* __restrict__ colsrc,
                                                  unsigned short* __restrict__ ub,
                                                  int n) {
  __shared__ float4 albuf[4][64];
  __shared__ int sbuf[4][64];
  const int lane = threadIdx.x & 63;
  const int wid = threadIdx.x >> 6;
  const int i = blockIdx.x * 4 + wid;
  if (i >= n) return;
  const float4 adv = *(const float4*)(a_d + i * 4);
  const float4 asv = *(const float4*)(a_s + i * 4);
  float es0 = lrelu02(asv.x + adv.x);
  float es1 = lrelu02(asv.y + adv.y);
  float es2 = lrelu02(asv.z + adv.z);
  float es3 = lrelu02(asv.w + adv.w);
  const int e0 = rowp[i], e1 = rowp[i + 1];
  // pass 1: max
  float m0 = es0, m1 = es1, m2 = es2, m3 = es3;
  for (int j = e0 + lane; j < e1; j += 64) {
    int s = colsrc[j];
    const float4 av = *(const float4*)(a_s + s * 4);
    m0 = fmaxf(m0, lrelu02(av.x + adv.x));
    m1 = fmaxf(m1, lrelu02(av.y + adv.y));
    m2 = fmaxf(m2, lrelu02(av.z + adv.z));
    m3 = fmaxf(m3, lrelu02(av.w + adv.w));
  }
#pragma unroll
  for (int m = 32; m >= 1; m >>= 1) {
    m0 = fmaxf(m0, __shfl_xor(m0, m));
    m1 = fmaxf(m1, __shfl_xor(m1, m));
    m2 = fmaxf(m2, __shfl_xor(m2, m));
    m3 = fmaxf(m3, __shfl_xor(m3, m));
  }
  // pass 2: denom
  float d0 = 0.f, d1 = 0.f, d2 = 0.f, d3 = 0.f;
  for (int j = e0 + lane; j < e1; j += 64) {
    int s = colsrc[j];
    const float4 av = *(const float4*)(a_s + s * 4);
    d0 += __expf(lrelu02(av.x + adv.x) - m0);
    d1 += __expf(lrelu02(av.y + adv.y) - m1);
    d2 += __expf(lrelu02(av.z + adv.z) - m2);
    d3 += __expf(lrelu02(av.w + adv.w) - m3);
  }
#pragma unroll
  for (int m = 32; m >= 1; m >>= 1) {
    d0 += __shfl_xor(d0, m);
    d1 += __shfl_xor(d1, m);
    d2 += __shfl_xor(d2, m);
    d3 += __shfl_xor(d3, m);
  }
  d0 += __expf(es0 - m0);
  d1 += __expf(es1 - m1);
  d2 += __expf(es2 - m2);
  d3 += __expf(es3 - m3);
  const float inv0 = 1.0f / d0, inv1 = 1.0f / d1, inv2 = 1.0f / d2, inv3 = 1.0f / d3;
  const float4 asf = make_float4(__expf(es0 - m0) * inv0, __expf(es1 - m1) * inv1,
                                 __expf(es2 - m2) * inv2, __expf(es3 - m3) * inv3);
  // accumulators: col c0=lane*2 (heads 0-3), col c0+1 (heads 0-3)
  const int c0 = lane * 2;
  uint32_t sv = *(const uint32_t*)(x2b + (size_t)i * HID + c0);
  float x0 = bflo(sv), x1 = bfhi(sv);
  float4 A0 = make_float4(x0 * asf.x, x0 * asf.y, x0 * asf.z, x0 * asf.w);
  float4 A1 = make_float4(x1 * asf.x, x1 * asf.y, x1 * asf.z, x1 * asf.w);
  // pass 3: chunked -- 64 lanes compute 64 edge-alphas, then stream x2 rows (4B/lane/edge)
  for (int b = e0; b < e1; b += 64) {
    int j = b + lane;
    if (j < e1) {
      int s = colsrc[j];
      const float4 av = *(const float4*)(a_s + s * 4);
      albuf[wid][lane] = make_float4(__expf(lrelu02(av.x + adv.x) - m0) * inv0,
                                     __expf(lrelu02(av.y + adv.y) - m1) * inv1,
                                     __expf(lrelu02(av.z + adv.z) - m2) * inv2,
                                     __expf(lrelu02(av.w + adv.w) - m3) * inv3);
      sbuf[wid][lane] = s;
    }
    asm volatile("s_waitcnt lgkmcnt(0)" ::: "memory");
    const int cnt = min(64, e1 - b);
    for (int t = 0; t < cnt; ++t) {
      float4 a4 = albuf[wid][t];
      int s = sbuf[wid][t];
      uint32_t wv = *(const uint32_t*)(x2b + (size_t)s * HID + c0);
      float w0 = bflo(wv), w1 = bfhi(wv);
      A0.x = fmaf(w0, a4.x, A0.x); A0.y = fmaf(w0, a4.y, A0.y);
      A0.z = fmaf(w0, a4.z, A0.z); A0.w = fmaf(w0, a4.w, A0.w);
      A1.x = fmaf(w1, a4.x, A1.x); A1.y = fmaf(w1, a4.y, A1.y);
      A1.z = fmaf(w1, a4.z, A1.z); A1.w = fmaf(w1, a4.w, A1.w);
    }
  }
  // write u[i][c0*4+h .. c0*4+7] = 8 bf16, coalesced 16B/lane
  uint4 o;
  o.x = (uint32_t)f2bf_rn(A0.x) | ((uint32_t)f2bf_rn(A0.y) << 16);
  o.y = (uint32_t)f2bf_rn(A0.z) | ((uint32_t)f2bf_rn(A0.w) << 16);
  o.z = (uint32_t)f2bf_rn(A1.x) | ((uint32_t)f2bf_rn(A1.y) << 16);
  o.w = (uint32_t)f2bf_rn(A1.z) | ((uint32_t)f2bf_rn(A1.w) << 16);
  *(uint4*)(ub + (size_t)i * GATD + lane * 8) = o;
}

extern "C" void kernel_launch(void* const* d_in, const int* in_sizes, int n_in,
                              void* d_out, int out_size, void* d_ws, size_t ws_size,
                              hipStream_t stream) {
  const float* x = (const float*)d_in[0];
  const int* ei = (const int*)d_in[1];
  const float* Win = (const float*)d_in[2];
  const float* bin = (const float*)d_in[3];
  const float* Wg1 = (const float*)d_in[4];
  const float* bg1 = (const float*)d_in[5];
  const float* g1g = (const float*)d_in[6];
  const float* g1b = (const float*)d_in[7];
  const float* Wg2 = (const float*)d_in[8];
  const float* bg2 = (const float*)d_in[9];
  const float* g2g = (const float*)d_in[10];
  const float* g2b = (const float*)d_in[11];
  const float* Wgat = (const float*)d_in[12];
  const float* att_s = (const float*)d_in[13];
  const float* att_d = (const float*)d_in[14];
  const float* bgat = (const float*)d_in[15];
  const float* Wao = (const float*)d_in[16];
  const float* bao = (const float*)d_in[17];
  const float* Wout = (const float*)d_in[18];
  const float* bout = (const float*)d_in[19];

  const int N = in_sizes[0] / 256;
  const int E = in_sizes[1] / 2;
  const int* src = ei;
  const int* dst = ei + E;

  // ---- workspace layout (bytes), ~120 MB ----
  char* base = (char*)d_ws;
  size_t off = 0;
  unsigned short* h0b = (unsigned short*)(base + off); off += (size_t)N * HID * 2;
  unsigned short* x1b = (unsigned short*)(base + off); off += (size_t)N * HID * 2;
  unsigned short* xwb = (unsigned short*)(base + off); off += (size_t)N * HID * 2;
  unsigned short* x2b = (unsigned short*)(base + off); off += (size_t)N * HID * 2;
  unsigned short* ub = (unsigned short*)(base + off); off += (size_t)N * GATD * 2;
  unsigned short* attb = h0b;  // h0 dead after Wg1 GEMM; att written after
  float* dinv = (float*)(base + off);                 off += (size_t)N * 4;
  float* a_s = (float*)(base + off);                  off += (size_t)N * 16;
  float* a_d = (float*)(base + off);                  off += (size_t)N * 16;
  float* waT = (float*)(base + off);                  off += 4096;
  float* cb = (float*)(base + off);                   off += 512;
  unsigned short *WinTh, *WinTl, *Wg1Th, *Wg1Tl, *Wg2Th, *Wg2Tl, *V2Th, *V2Tl;
  unsigned short *WoutTh, *WoutTl;
  WinTh = (unsigned short*)(base + off); off += 256 * 128 * 2;
  WinTl = (unsigned short*)(base + off); off += 256 * 128 * 2;
  Wg1Th = (unsigned short*)(base + off); off += 128 * 128 * 2;
  Wg1Tl = (unsigned short*)(base + off); off += 128 * 128 * 2;
  Wg2Th = (unsigned short*)(base + off); off += 128 * 128 * 2;
  Wg2Tl = (unsigned short*)(base + off); off += 128 * 128 * 2;
  V2Th = (unsigned short*)(base + off);  off += 512 * 128 * 2;
  V2Tl = (unsigned short*)(base + off);  off += 512 * 128 * 2;
  WoutTh = (unsigned short*)(base + off); off += 128 * 64 * 2;
  WoutTl = (unsigned short*)(base + off); off += 128 * 64 * 2;
  int* rowp = (int*)(base + off);   off += (size_t)(N + 1) * 4;
  int* colsrc = (int*)(base + off); off += (size_t)E * 4;
  const int nb2 = (N + 1023) / 1024;
  int* bsum = (int*)(base + off);   off += (size_t)(nb2 + 2) * 4;
  int* cnt = (int*)ub;  // alias: dead before ub is written
  int* cur = cnt + N;

  const int eb = (E + TPB - 1) / TPB;
  const int zbk = (2 * N + TPB - 1) / TPB;
  const int ab = (N + 3) / 4;
  const int gm = (N + 63) / 64;

  // CSR + prep
  k_zero<<<zbk, TPB, 0, stream>>>(cnt, 2 * N);
  k_hist<<<eb, TPB, 0, stream>>>(dst, cnt, E);
  k_scan_blk<<<nb2, 256, 0, stream>>>(cnt, rowp, bsum, dinv, N);
  k_scan_top<<<1, 256, 0, stream>>>(bsum, nb2);
  k_scan_add<<<(N + 255) / 256, 256, 0, stream>>>(rowp, bsum, N, nb2);
  k_fill<<<eb, TPB, 0, stream>>>(src, dst, rowp, cur, colsrc, E);
  k_prep<<<(1024 + 65536 + 128 + 255) / 256, 256, 0, stream>>>(
      Wgat, att_s, att_d, Wao, bgat, bao, waT, V2Th, V2Tl, cb);
  k_splitw_all<<<(73728 + 255) / 256, 256, 0, stream>>>(
      Win, Wg1, Wg2, Wout, WinTh, WinTl, Wg1Th, Wg1Tl, Wg2Th, Wg2Tl, WoutTh, WoutTl);

  // h0 = relu(x @ Win + bin) -> bf16     [fp32 A converted in regs]
  k_gemm6<256, 64, 128, true, true, 1, 1><<<dim3(gm, 1), 256, 0, stream>>>(
      x, WinTh, WinTl, bin, h0b, N, 128);
  // GCN layer 1: xwb = bf16(h0 @ Wg1)
  k_gemm6<128, 64, 128, false, false, 1, 0><<<dim3(gm, 1), 256, 0, stream>>>(
      h0b, Wg1Th, Wg1Tl, nullptr, xwb, N, 128);
  k_gcn_agg<false><<<ab, 256, 0, stream>>>(xwb, dinv, rowp, colsrc, bg1, g1g, g1b,
                                           nullptr, x1b, nullptr, nullptr, nullptr, N);
  // GCN layer 2 (+residual, +fused GAT logits)
  k_gemm6<128, 64, 128, false, false, 1, 0><<<dim3(gm, 1), 256, 0, stream>>>(
      x1b, Wg2Th, Wg2Tl, nullptr, xwb, N, 128);
  k_gcn_agg<true><<<ab, 256, 0, stream>>>(xwb, dinv, rowp, colsrc, bg2, g2g, g2b,
                                          x1b, x2b, waT, a_s, a_d, N);
  // GAT aggregate on x2 directly (V commuted out): u[N,512] bf16
  k_gat_agg4<<<ab, 256, 0, stream>>>(x2b, a_s, a_d, rowp, colsrc, ub, N);
  // att = relu(u @ V2 + cb) -> bf16 (attb aliases dead h0b)
  k_gemm6<512, 64, 128, true, true, 1, 0><<<dim3(gm, 1), 256, 0, stream>>>(
      ub, V2Th, V2Tl, cb, attb, N, 128);
  // out = att @ Wout + bout -> fp32
  k_gemm6<128, 128, 64, false, true, 0, 0><<<dim3(gm, 1), 256, 0, stream>>>(
      attb, WoutTh, WoutTl, bout, (float*)d_out, N, 64);
}